// Round 9
// baseline (718.882 us; speedup 1.0000x reference)
//
#include <hip/hip_runtime.h>
#include <hip/hip_bf16.h>

#define N_NODES 100000
#define N_INCID 2000000
#define N_HEDGES 300000
#define IN_DIM 92
#define H_DIM 64
#define ATTR_DIM 35
#define ATTR_PAIRS 18
#define HOUT_DIM 128
#define N_GRAPHS 512
#define N_LAYERS 3
#define MSG_DIM 163
#define KPAIRS 96        // layer K padded to 192 bf16 = 96 uint pairs
#define ZLDS 100         // layer LDS row stride in uints
#define EPAIRS 48        // embed K padded to 96 bf16 = 48 pairs
#define ELDS 50          // embed LDS row stride in uints

// sort geometry
#define IPB 8192
#define NBLK 245
#define ESHIFT 9
#define NB_E 586
#define NSHIFT 8
#define NB_N 391
#define VALBITS 21       // N_INCID < 2^21

typedef short bf16x8 __attribute__((ext_vector_type(8)));
typedef float f32x4 __attribute__((ext_vector_type(4)));
typedef float f32x2 __attribute__((ext_vector_type(2)));

__device__ __forceinline__ float softplusf(float x) {
    return fmaxf(x, 0.f) + __logf(1.f + __expf(-fabsf(x)));
}
__device__ __forceinline__ float sigmoidf(float x) {
    return __builtin_amdgcn_rcpf(1.f + __expf(-x));
}
__device__ __forceinline__ float u2f(unsigned u) {
    union { unsigned u; float f; } x; x.u = u; return x.f;
}
__device__ __forceinline__ float2 bf2_to_f2(unsigned v) {
    return make_float2(u2f(v << 16), u2f(v & 0xffff0000u));
}
__device__ __forceinline__ unsigned f2_to_bf2(float x, float y) {
    union { float f; unsigned u; } a, b;
    a.f = x; b.f = y;
    unsigned lo = (a.u + 0x7fffu + ((a.u >> 16) & 1u)) >> 16;
    unsigned hi = ((b.u + 0x7fffu + ((b.u >> 16) & 1u)) >> 16) << 16;
    return lo | hi;
}

// ---------- W_embed -> bf16 Bt [c=64][p=48] ----------
__global__ void embpack_k(const float* __restrict__ W, unsigned* __restrict__ BtE) {
    int idx = blockIdx.x * 256 + threadIdx.x;
    if (idx >= 64 * EPAIRS) return;
    int c = idx / EPAIRS, p = idx - c * EPAIRS;
    int k0 = 2 * p, k1 = 2 * p + 1;
    float v0 = (k0 < IN_DIM) ? W[k0 * 64 + c] : 0.f;
    float v1 = (k1 < IN_DIM) ? W[k1 * 64 + c] : 0.f;
    BtE[idx] = f2_to_bf2(v0, v1);
}

// ---------- embed via MFMA ----------
__global__ void __launch_bounds__(256)
embed_mfma_k(const float* __restrict__ x, const unsigned* __restrict__ BtE,
             const float* __restrict__ be, const int* __restrict__ ncnt,
             float* __restrict__ h, unsigned* __restrict__ hb,
             unsigned* __restrict__ zb) {
    __shared__ unsigned zsu[64][ELDS];
    __shared__ unsigned btu[64][ELDS];
    int node0 = blockIdx.x * 64;
    int t = threadIdx.x;
    for (int idx = t; idx < 64 * EPAIRS; idx += 256) {
        int r = idx / EPAIRS, p = idx - r * EPAIRS;
        int node = node0 + r;
        unsigned pr = 0u;
        if (node < N_NODES && p < 46) {
            float2 f = *(const float2*)(x + (size_t)node * IN_DIM + 2 * p);
            pr = f2_to_bf2(f.x, f.y);
        }
        zsu[r][p] = pr;
    }
    for (int idx = t; idx < 64 * EPAIRS; idx += 256) {
        int c = idx / EPAIRS, p = idx - c * EPAIRS;
        btu[c][p] = BtE[idx];
    }
    __syncthreads();
    int w = t >> 6, lane = t & 63, row16 = lane & 15, kg = lane >> 4;
    f32x4 acc[4];
#pragma unroll
    for (int n = 0; n < 4; ++n) acc[n] = (f32x4){0.f, 0.f, 0.f, 0.f};
#pragma unroll
    for (int ks = 0; ks < 3; ++ks) {
        int pbase = ks * 16 + kg * 4;
        bf16x8 a = *(const bf16x8*)&zsu[w * 16 + row16][pbase];
#pragma unroll
        for (int n = 0; n < 4; ++n) {
            bf16x8 b = *(const bf16x8*)&btu[n * 16 + row16][pbase];
            acc[n] = __builtin_amdgcn_mfma_f32_16x16x32_bf16(a, b, acc[n], 0, 0, 0);
        }
    }
#pragma unroll
    for (int i = 0; i < 4; ++i) {
        int node = node0 + w * 16 + kg * 4 + i;
        if (node < N_NODES) {
            bool has = ncnt[node] > 0;
#pragma unroll
            for (int n = 0; n < 4; ++n) {
                int d = n * 16 + row16;
                float nv = acc[n][i] + be[d];
                h[node * 64 + d] = nv;
                float other = __shfl_xor(nv, 1);
                if ((d & 1) == 0) {
                    unsigned pr = f2_to_bf2(nv, other);
                    hb[node * 32 + (d >> 1)] = pr;
                    zb[(size_t)node * KPAIRS + (d >> 1)] = has ? pr : 0u;
                }
            }
        }
    }
}

// ---------- hattr -> bf16 padded mirror ----------
__global__ void attrconv_k(const float* __restrict__ hattr, unsigned* __restrict__ hab) {
    int idx = blockIdx.x * 256 + threadIdx.x;
    if (idx >= N_HEDGES * ATTR_PAIRS) return;
    int e = idx / ATTR_PAIRS, p = idx - e * ATTR_PAIRS;
    int d0 = 2 * p, d1 = 2 * p + 1;
    float v0 = hattr[e * ATTR_DIM + d0];
    float v1 = (d1 < ATTR_DIM) ? hattr[e * ATTR_DIM + d1] : 0.f;
    hab[idx] = f2_to_bf2(v0, v1);
}

// ---------- layer weights -> Bt bf16 [l][c=128][k pairs=96] ----------
__global__ void btpack_k(const float* __restrict__ Wf, const float* __restrict__ Wc,
                         unsigned* __restrict__ Btb) {
    int idx = blockIdx.x * 256 + threadIdx.x;
    if (idx >= N_LAYERS * 128 * KPAIRS) return;
    int l = idx / (128 * KPAIRS);
    int rem = idx - l * 128 * KPAIRS;
    int c = rem / KPAIRS, p = rem - c * KPAIRS;
    int k0 = 2 * p, k1 = 2 * p + 1;
    const float* W = (c < 64) ? (Wf + (size_t)l * MSG_DIM * 64) : (Wc + (size_t)l * MSG_DIM * 64);
    int cc = c & 63;
    float v0 = (k0 < MSG_DIM) ? W[k0 * 64 + cc] : 0.f;
    float v1 = (k1 < MSG_DIM) ? W[k1 * 64 + cc] : 0.f;
    Btb[idx] = f2_to_bf2(v0, v1);
}

// ---------- sort S1 ----------
__global__ void sorthist_k(const int* __restrict__ key, int* __restrict__ hist,
                           int kshift, int NB) {
    __shared__ int cnt[640];
    int blk = blockIdx.x;
    for (int i = threadIdx.x; i < NB; i += 256) cnt[i] = 0;
    __syncthreads();
    int base = blk * IPB;
    int end = min(base + IPB, N_INCID);
    for (int i = base + threadIdx.x; i < end; i += 256)
        atomicAdd(&cnt[key[i] >> kshift], 1);
    __syncthreads();
    for (int i = threadIdx.x; i < NB; i += 256) hist[blk * NB + i] = cnt[i];
}

// ---------- scan with bucket-major remap ----------
__global__ void scanR1_k(const int* __restrict__ in, int* __restrict__ out,
                         int* __restrict__ bsum, int n, int NB) {
    __shared__ int tmp[256];
    int gid = blockIdx.x * 256 + threadIdx.x;
    int v = 0;
    if (gid < n) {
        int bucket = gid / NBLK, blk = gid - bucket * NBLK;
        v = in[blk * NB + bucket];
    }
    tmp[threadIdx.x] = v;
    __syncthreads();
    for (int o = 1; o < 256; o <<= 1) {
        int t = (threadIdx.x >= o) ? tmp[threadIdx.x - o] : 0;
        __syncthreads();
        tmp[threadIdx.x] += t;
        __syncthreads();
    }
    if (gid < n) out[gid] = tmp[threadIdx.x] - v;
    if (threadIdx.x == 255) bsum[blockIdx.x] = tmp[255];
}

__global__ void scan2_k(int* __restrict__ bsum, int nb) {
    __shared__ int tmp[256];
    __shared__ int carry;
    if (threadIdx.x == 0) carry = 0;
    __syncthreads();
    for (int base = 0; base < nb; base += 256) {
        int gid = base + threadIdx.x;
        int v = (gid < nb) ? bsum[gid] : 0;
        tmp[threadIdx.x] = v;
        __syncthreads();
        for (int o = 1; o < 256; o <<= 1) {
            int t = (threadIdx.x >= o) ? tmp[threadIdx.x - o] : 0;
            __syncthreads();
            tmp[threadIdx.x] += t;
            __syncthreads();
        }
        if (gid < nb) bsum[gid] = tmp[threadIdx.x] - v + carry;
        __syncthreads();
        if (threadIdx.x == 0) carry += tmp[255];
        __syncthreads();
    }
}

__global__ void scan3_k(int* __restrict__ out, const int* __restrict__ bsum, int n) {
    int gid = blockIdx.x * 256 + threadIdx.x;
    if (gid < n) out[gid] += bsum[blockIdx.x];
}

// ---------- sort S3: scatter (key low bits | val) packed in 32 bits ----------
__global__ void sortscat_k(const int* __restrict__ key, const int* __restrict__ val,
                           const int* __restrict__ soff, unsigned* __restrict__ stage,
                           int kshift, int NB) {
    __shared__ int cur[640], bas[640];
    int blk = blockIdx.x;
    for (int i = threadIdx.x; i < NB; i += 256) {
        cur[i] = 0;
        bas[i] = soff[i * NBLK + blk];
    }
    __syncthreads();
    int base = blk * IPB;
    int end = min(base + IPB, N_INCID);
    unsigned kmaskbits = (1u << kshift) - 1u;
    for (int i = base + threadIdx.x; i < end; i += 256) {
        int k = key[i], b = k >> kshift;
        int d = bas[b] + atomicAdd(&cur[b], 1);
        stage[d] = (((unsigned)k & kmaskbits) << VALBITS) | (unsigned)val[i];
    }
}

// ---------- sort S4: fine counting-sort within bucket (parallel LDS scan) ----------
__global__ void sortfine_k(const unsigned* __restrict__ stage, const int* __restrict__ soff,
                           int* __restrict__ csr, int* __restrict__ koff,
                           float* __restrict__ krcp, int* __restrict__ kcnt,
                           int kshift, int NB, int NKEYS) {
    __shared__ int cnt[512], off[512], cur[512];
    __shared__ int ts[256];
    int b = blockIdx.x;
    int tid = threadIdx.x;
    int KPB = 1 << kshift;
    int kbase = b << kshift;
    int base = soff[b * NBLK];
    int end = (b == NB - 1) ? N_INCID : soff[(b + 1) * NBLK];
    for (int i = tid; i < KPB; i += 256) cnt[i] = 0;
    __syncthreads();
    for (int i = base + tid; i < end; i += 256)
        atomicAdd(&cnt[stage[i] >> VALBITS], 1);
    __syncthreads();
    // exclusive scan of cnt[0..KPB) via pair-based Hillis-Steele
    int half = KPB >> 1;
    int c0 = 0, c1 = 0;
    if (tid < half) { c0 = cnt[2 * tid]; c1 = cnt[2 * tid + 1]; ts[tid] = c0 + c1; }
    __syncthreads();
    for (int o = 1; o < 256; o <<= 1) {
        int v = (tid >= o && tid < half) ? ts[tid - o] : 0;
        __syncthreads();
        if (tid < half) ts[tid] += v;
        __syncthreads();
    }
    if (tid < half) {
        int ex = ts[tid] - (c0 + c1);
        off[2 * tid] = ex;
        off[2 * tid + 1] = ex + c0;
    }
    __syncthreads();
    for (int k = tid; k < KPB; k += 256) {
        int gk = kbase + k;
        if (gk < NKEYS) {
            koff[gk] = base + off[k];
            krcp[gk] = 1.0f / (float)max(cnt[k], 1);
            kcnt[gk] = cnt[k];
        }
        cur[k] = 0;
    }
    __syncthreads();
    for (int i = base + tid; i < end; i += 256) {
        unsigned it = stage[i];
        int lk = (int)(it >> VALBITS);
        int pos = base + off[lk] + atomicAdd(&cur[lk], 1);
        csr[pos] = (int)(it & ((1u << VALBITS) - 1u));
    }
}

__global__ void sentinel_k(int* __restrict__ eoff, int* __restrict__ noff) {
    if (threadIdx.x == 0) eoff[N_HEDGES] = N_INCID;
    if (threadIdx.x == 1) noff[N_NODES] = N_INCID;
}

// ---------- per-hedge mean: uint2/lane, 16 lanes/row, packed f32x2 accumulate ----------
__global__ void hmean_k(const int* __restrict__ eoff, const int* __restrict__ csr_en,
                        const uint2* __restrict__ hbv, const float* __restrict__ ercp,
                        uint2* __restrict__ hmv) {
    int idx = blockIdx.x * 256 + threadIdx.x;
    int e = idx >> 5, l = idx & 31;
    if (e >= N_HEDGES) return;
    int sub = l >> 4, q = l & 15;
    int s = eoff[e], t = eoff[e + 1];
    f32x2 A01 = {0.f, 0.f}, A23 = {0.f, 0.f};
    for (int base = s; base < t; base += 32) {
        int cnt = min(32, t - base);
        int myidx = (base + l < t) ? csr_en[base + l] : 0;
        for (int j = 0; j < cnt; j += 16) {
            uint2 v[8];
#pragma unroll
            for (int w = 0; w < 8; ++w) {
                int mem = j + 2 * w + sub;
                int nq = __shfl(myidx, mem, 32);
                v[w] = (mem < cnt) ? hbv[nq * 16 + q] : make_uint2(0u, 0u);
            }
#pragma unroll
            for (int w = 0; w < 8; ++w) {
                A01 += (f32x2){u2f(v[w].x << 16), u2f(v[w].x)};
                A23 += (f32x2){u2f(v[w].y << 16), u2f(v[w].y)};
            }
        }
    }
    float a0 = A01.x + __shfl_xor(A01.x, 16);
    float a1 = A01.y + __shfl_xor(A01.y, 16);
    float a2 = A23.x + __shfl_xor(A23.x, 16);
    float a3 = A23.y + __shfl_xor(A23.y, 16);
    if (sub == 0) {
        float rc = ercp[e];
        hmv[e * 16 + q] = make_uint2(f2_to_bf2(a0 * rc, a1 * rc), f2_to_bf2(a2 * rc, a3 * rc));
    }
}

// ---------- per-node mean of hmean -> zb pairs 32..63 ----------
__global__ void nodeh_k(const int* __restrict__ noff, const int* __restrict__ csr_ne,
                        const uint2* __restrict__ hmv, const float* __restrict__ nrcp,
                        uint2* __restrict__ zbv) {
    int idx = blockIdx.x * 256 + threadIdx.x;
    int n = idx >> 5, l = idx & 31;
    if (n >= N_NODES) return;
    int sub = l >> 4, q = l & 15;
    int s = noff[n], t = noff[n + 1];
    f32x2 A01 = {0.f, 0.f}, A23 = {0.f, 0.f};
    for (int base = s; base < t; base += 32) {
        int cnt = min(32, t - base);
        int myidx = (base + l < t) ? csr_ne[base + l] : 0;
        for (int j = 0; j < cnt; j += 16) {
            uint2 v[8];
#pragma unroll
            for (int w = 0; w < 8; ++w) {
                int mem = j + 2 * w + sub;
                int eq = __shfl(myidx, mem, 32);
                v[w] = (mem < cnt) ? hmv[eq * 16 + q] : make_uint2(0u, 0u);
            }
#pragma unroll
            for (int w = 0; w < 8; ++w) {
                A01 += (f32x2){u2f(v[w].x << 16), u2f(v[w].x)};
                A23 += (f32x2){u2f(v[w].y << 16), u2f(v[w].y)};
            }
        }
    }
    float a0 = A01.x + __shfl_xor(A01.x, 16);
    float a1 = A01.y + __shfl_xor(A01.y, 16);
    float a2 = A23.x + __shfl_xor(A23.x, 16);
    float a3 = A23.y + __shfl_xor(A23.y, 16);
    if (sub == 0) {
        float rc = nrcp[n];
        zbv[(size_t)n * (KPAIRS / 2) + 16 + q] =
            make_uint2(f2_to_bf2(a0 * rc, a1 * rc), f2_to_bf2(a2 * rc, a3 * rc));
    }
}

// ---------- per-node mean of hedge_attr -> zb pairs 64..95 (one-time) ----------
__global__ void nodea_k(const int* __restrict__ noff, const int* __restrict__ csr_ne,
                        const uint2* __restrict__ habv, const float* __restrict__ nrcp,
                        uint2* __restrict__ zbv) {
    int idx = blockIdx.x * 256 + threadIdx.x;
    int n = idx >> 5, l = idx & 31;
    if (n >= N_NODES) return;
    int sub = l >> 4, q = l & 15;
    bool act = (q < ATTR_PAIRS / 2);
    int s = noff[n], t = noff[n + 1];
    f32x2 A01 = {0.f, 0.f}, A23 = {0.f, 0.f};
    for (int base = s; base < t; base += 32) {
        int cnt = min(32, t - base);
        int myidx = (base + l < t) ? csr_ne[base + l] : 0;
        for (int j = 0; j < cnt; j += 16) {
            uint2 v[8];
#pragma unroll
            for (int w = 0; w < 8; ++w) {
                int mem = j + 2 * w + sub;
                int eq = __shfl(myidx, mem, 32);
                v[w] = (act && mem < cnt) ? habv[eq * (ATTR_PAIRS / 2) + q] : make_uint2(0u, 0u);
            }
#pragma unroll
            for (int w = 0; w < 8; ++w) {
                A01 += (f32x2){u2f(v[w].x << 16), u2f(v[w].x)};
                A23 += (f32x2){u2f(v[w].y << 16), u2f(v[w].y)};
            }
        }
    }
    float a0 = A01.x + __shfl_xor(A01.x, 16);
    float a1 = A01.y + __shfl_xor(A01.y, 16);
    float a2 = A23.x + __shfl_xor(A23.x, 16);
    float a3 = A23.y + __shfl_xor(A23.y, 16);
    if (sub == 0) {
        float rc = nrcp[n];
        uint2 pr = act ? make_uint2(f2_to_bf2(a0 * rc, a1 * rc), f2_to_bf2(a2 * rc, a3 * rc))
                       : make_uint2(0u, 0u);
        zbv[(size_t)n * (KPAIRS / 2) + 32 + q] = pr;
    }
}

// ---------- layer GEMM via MFMA; B in registers, A in LDS ----------
__global__ void __launch_bounds__(256)
layer_mfma_k(const unsigned* __restrict__ Btl, const float* __restrict__ bfv,
             const float* __restrict__ bcv, const int* __restrict__ ncnt,
             unsigned* __restrict__ zb, float* __restrict__ h,
             unsigned* __restrict__ hb) {
    __shared__ unsigned zsu[64][ZLDS];
    int node0 = blockIdx.x * 64;
    int t = threadIdx.x;
    int w = t >> 6, lane = t & 63;
    int row16 = lane & 15, kg = lane >> 4;

    uint4 bregF[6], bregC[6];
    {
        const uint4* bv = (const uint4*)Btl;
        int colF = w * 16 + row16;
        int colC = colF + 64;
#pragma unroll
        for (int ks = 0; ks < 6; ++ks) {
            bregF[ks] = bv[colF * 24 + ks * 4 + kg];
            bregC[ks] = bv[colC * 24 + ks * 4 + kg];
        }
    }
    {
        const uint4* zv = (const uint4*)zb;
        for (int idx = t; idx < 64 * 24; idx += 256) {
            int r = idx / 24, p4 = idx - r * 24;
            int node = node0 + r;
            uint4 v = make_uint4(0u, 0u, 0u, 0u);
            if (node < N_NODES) v = zv[(size_t)node * 24 + p4];
            *(uint4*)&zsu[r][p4 * 4] = v;
        }
    }
    __syncthreads();

    f32x4 accF[4], accC[4];
#pragma unroll
    for (int n = 0; n < 4; ++n) {
        accF[n] = (f32x4){0.f, 0.f, 0.f, 0.f};
        accC[n] = (f32x4){0.f, 0.f, 0.f, 0.f};
    }

#pragma unroll
    for (int ks = 0; ks < 6; ++ks) {
        int pbase = ks * 16 + kg * 4;
        bf16x8 bF = *(const bf16x8*)&bregF[ks];
        bf16x8 bC = *(const bf16x8*)&bregC[ks];
#pragma unroll
        for (int rb = 0; rb < 4; ++rb) {
            bf16x8 a = *(const bf16x8*)&zsu[rb * 16 + row16][pbase];
            accF[rb] = __builtin_amdgcn_mfma_f32_16x16x32_bf16(a, bF, accF[rb], 0, 0, 0);
            accC[rb] = __builtin_amdgcn_mfma_f32_16x16x32_bf16(a, bC, accC[rb], 0, 0, 0);
        }
    }

    int d = w * 16 + row16;
    float bfd = bfv[d], bcd = bcv[d];
#pragma unroll
    for (int rb = 0; rb < 4; ++rb) {
#pragma unroll
        for (int i = 0; i < 4; ++i) {
            int node = node0 + rb * 16 + kg * 4 + i;
            if (node < N_NODES) {
                bool has = ncnt[node] > 0;
                float f = accF[rb][i] + bfd;
                float c = accC[rb][i] + bcd;
                float hv = h[node * 64 + d];
                float nv = softplusf(sigmoidf(f) * softplusf(c) + hv);
                h[node * 64 + d] = nv;
                float other = __shfl_xor(nv, 1);
                if ((d & 1) == 0) {
                    unsigned pr = f2_to_bf2(nv, other);
                    hb[node * 32 + (d >> 1)] = pr;
                    zb[(size_t)node * KPAIRS + (d >> 1)] = has ? pr : 0u;
                }
            }
        }
    }
}

// ---------- per-graph boundaries ----------
__global__ void gstart_k(const int* __restrict__ batch, int* __restrict__ gstart) {
    int g = blockIdx.x * 256 + threadIdx.x;
    if (g > N_GRAPHS) return;
    int lo = 0, hi = N_NODES;
    while (lo < hi) {
        int mid = (lo + hi) >> 1;
        if (batch[mid] < g) lo = mid + 1; else hi = mid;
    }
    gstart[g] = lo;
}

// ---------- fused pool + proj + out ----------
__global__ void poolhead_k(const float* __restrict__ h, const int* __restrict__ gstart,
                           const float* __restrict__ Wp, const float* __restrict__ bp,
                           const float* __restrict__ Wo, const float* __restrict__ bo,
                           float* __restrict__ out) {
    __shared__ float partial[4][64];
    __shared__ float pm[64];
    __shared__ float pr[128];
    int g = blockIdx.x, t = threadIdx.x;
    int s = gstart[g], e = gstart[g + 1];
    int w = t >> 6, lane = t & 63;
    float acc = 0.f;
    for (int n = s + w; n < e; n += 4) acc += h[n * 64 + lane];
    partial[w][lane] = acc;
    __syncthreads();
    if (t < 64) {
        float c = fmaxf((float)(e - s), 1.0f);
        pm[t] = (partial[0][t] + partial[1][t] + partial[2][t] + partial[3][t]) / c;
    }
    __syncthreads();
    if (t < 128) {
        float a = bp[t];
#pragma unroll 4
        for (int k = 0; k < 64; ++k) a += pm[k] * Wp[k * HOUT_DIM + t];
        pr[t] = softplusf(a) * Wo[t];
    }
    __syncthreads();
    if (t < 64) {
        float v = pr[t] + pr[t + 64];
        for (int o = 32; o > 0; o >>= 1) v += __shfl_down(v, o);
        if (t == 0) out[g] = v + bo[0];
    }
}

extern "C" void kernel_launch(void* const* d_in, const int* in_sizes, int n_in,
                              void* d_out, int out_size, void* d_ws, size_t ws_size,
                              hipStream_t stream) {
    const float* x       = (const float*)d_in[0];
    const int*   inc_n   = (const int*)d_in[1];
    const int*   inc_e   = (const int*)d_in[2];
    const float* hattr   = (const float*)d_in[3];
    const int*   batch   = (const int*)d_in[4];
    const float* W_embed = (const float*)d_in[5];
    const float* b_embed = (const float*)d_in[6];
    const float* Wf      = (const float*)d_in[7];
    const float* bf      = (const float*)d_in[8];
    const float* Wc      = (const float*)d_in[9];
    const float* bc      = (const float*)d_in[10];
    const float* W_proj  = (const float*)d_in[11];
    const float* b_proj  = (const float*)d_in[12];
    const float* W_out   = (const float*)d_in[13];
    const float* b_out   = (const float*)d_in[14];
    float* out = (float*)d_out;

    char* ws = (char*)d_ws;
    size_t off = 0;
    auto alloc = [&](size_t bytes) {
        void* p = ws + off;
        off = (off + bytes + 255) & ~(size_t)255;
        return p;
    };
    float*    h      = (float*)alloc((size_t)N_NODES * 64 * 4);
    unsigned* hb     = (unsigned*)alloc((size_t)N_NODES * 32 * 4);
    unsigned* hmean  = (unsigned*)alloc((size_t)N_HEDGES * 32 * 4);  // aliases sort staging
    unsigned* zb     = (unsigned*)alloc((size_t)N_NODES * KPAIRS * 4);
    unsigned* hab    = (unsigned*)alloc((size_t)N_HEDGES * ATTR_PAIRS * 4);
    unsigned* Btb    = (unsigned*)alloc((size_t)N_LAYERS * 128 * KPAIRS * 4);
    unsigned* BtE    = (unsigned*)alloc((size_t)64 * EPAIRS * 4);
    int*      ncnt   = (int*)alloc((size_t)N_NODES * 4);
    int*      ecnt   = (int*)alloc((size_t)N_HEDGES * 4);
    float*    nrcp   = (float*)alloc((size_t)N_NODES * 4);
    float*    ercp   = (float*)alloc((size_t)N_HEDGES * 4);
    int*      eoff   = (int*)alloc((size_t)(N_HEDGES + 1) * 4);
    int*      noff   = (int*)alloc((size_t)(N_NODES + 1) * 4);
    int*      csr_en = (int*)alloc((size_t)N_INCID * 4);
    int*      csr_ne = (int*)alloc((size_t)N_INCID * 4);
    int*      hist   = (int*)alloc((size_t)NB_E * NBLK * 4);
    int*      soff   = (int*)alloc((size_t)NB_E * NBLK * 4);
    int*      bsum   = (int*)alloc((size_t)2048 * 4);
    int*      gstart = (int*)alloc((size_t)(N_GRAPHS + 1) * 4);
    unsigned* stage  = (unsigned*)hmean;

    // ---- hedge-side sort ----
    {
        int nlog = NB_E * NBLK;
        int nsb = (nlog + 255) / 256;
        sorthist_k<<<NBLK, 256, 0, stream>>>(inc_e, hist, ESHIFT, NB_E);
        scanR1_k<<<nsb, 256, 0, stream>>>(hist, soff, bsum, nlog, NB_E);
        scan2_k<<<1, 256, 0, stream>>>(bsum, nsb);
        scan3_k<<<nsb, 256, 0, stream>>>(soff, bsum, nlog);
        sortscat_k<<<NBLK, 256, 0, stream>>>(inc_e, inc_n, soff, stage, ESHIFT, NB_E);
        sortfine_k<<<NB_E, 256, 0, stream>>>(stage, soff, csr_en, eoff, ercp, ecnt,
                                             ESHIFT, NB_E, N_HEDGES);
    }
    // ---- node-side sort ----
    {
        int nlog = NB_N * NBLK;
        int nsb = (nlog + 255) / 256;
        sorthist_k<<<NBLK, 256, 0, stream>>>(inc_n, hist, NSHIFT, NB_N);
        scanR1_k<<<nsb, 256, 0, stream>>>(hist, soff, bsum, nlog, NB_N);
        scan2_k<<<1, 256, 0, stream>>>(bsum, nsb);
        scan3_k<<<nsb, 256, 0, stream>>>(soff, bsum, nlog);
        sortscat_k<<<NBLK, 256, 0, stream>>>(inc_n, inc_e, soff, stage, NSHIFT, NB_N);
        sortfine_k<<<NB_N, 256, 0, stream>>>(stage, soff, csr_ne, noff, nrcp, ncnt,
                                             NSHIFT, NB_N, N_NODES);
    }
    sentinel_k<<<1, 64, 0, stream>>>(eoff, noff);

    embpack_k<<<(64 * EPAIRS + 255) / 256, 256, 0, stream>>>(W_embed, BtE);
    embed_mfma_k<<<(N_NODES + 63) / 64, 256, 0, stream>>>(x, BtE, b_embed, ncnt, h, hb, zb);
    attrconv_k<<<(N_HEDGES * ATTR_PAIRS + 255) / 256, 256, 0, stream>>>(hattr, hab);
    btpack_k<<<(N_LAYERS * 128 * KPAIRS + 255) / 256, 256, 0, stream>>>(Wf, Wc, Btb);
    nodea_k<<<(N_NODES * 32) / 256, 256, 0, stream>>>(noff, csr_ne, (const uint2*)hab, nrcp,
                                                      (uint2*)zb);

    for (int l = 0; l < N_LAYERS; ++l) {
        hmean_k<<<(N_HEDGES * 32) / 256, 256, 0, stream>>>(eoff, csr_en, (const uint2*)hb, ercp,
                                                           (uint2*)hmean);
        nodeh_k<<<(N_NODES * 32) / 256, 256, 0, stream>>>(noff, csr_ne, (const uint2*)hmean, nrcp,
                                                          (uint2*)zb);
        layer_mfma_k<<<(N_NODES + 63) / 64, 256, 0, stream>>>(Btb + (size_t)l * 128 * KPAIRS,
                                                              bf + l * 64, bc + l * 64,
                                                              ncnt, zb, h, hb);
    }
    gstart_k<<<(N_GRAPHS + 1 + 255) / 256, 256, 0, stream>>>(batch, gstart);
    poolhead_k<<<N_GRAPHS, 256, 0, stream>>>(h, gstart, W_proj, b_proj, W_out, b_out, out);
}

// Round 10
// 662.300 us; speedup vs baseline: 1.0854x; 1.0854x over previous
//
#include <hip/hip_runtime.h>
#include <hip/hip_bf16.h>

#define N_NODES 100000
#define N_INCID 2000000
#define N_HEDGES 300000
#define IN_DIM 92
#define H_DIM 64
#define ATTR_DIM 35
#define ATTR_PAIRS 18
#define HOUT_DIM 128
#define N_GRAPHS 512
#define N_LAYERS 3
#define MSG_DIM 163
#define KPAIRS 96        // layer K padded to 192 bf16 = 96 uint pairs
#define ZLDS 100         // layer LDS row stride in uints
#define EPAIRS 48        // embed K padded to 96 bf16 = 48 pairs
#define ELDS 50          // embed LDS row stride in uints

// sort geometry
#define IPB 8192
#define NBLK 245
#define ESHIFT 9
#define NB_E 586
#define NSHIFT 8
#define NB_N 391
#define VALBITS 21       // N_INCID < 2^21

typedef short bf16x8 __attribute__((ext_vector_type(8)));
typedef float f32x4 __attribute__((ext_vector_type(4)));

__device__ __forceinline__ float softplusf(float x) {
    return fmaxf(x, 0.f) + __logf(1.f + __expf(-fabsf(x)));
}
__device__ __forceinline__ float sigmoidf(float x) {
    return __builtin_amdgcn_rcpf(1.f + __expf(-x));
}
__device__ __forceinline__ float u2f(unsigned u) {
    union { unsigned u; float f; } x; x.u = u; return x.f;
}
__device__ __forceinline__ unsigned f2_to_bf2(float x, float y) {
    union { float f; unsigned u; } a, b;
    a.f = x; b.f = y;
    unsigned lo = (a.u + 0x7fffu + ((a.u >> 16) & 1u)) >> 16;
    unsigned hi = ((b.u + 0x7fffu + ((b.u >> 16) & 1u)) >> 16) << 16;
    return lo | hi;
}

// ---------- W_embed -> bf16 Bt [c=64][p=48] ----------
__global__ void embpack_k(const float* __restrict__ W, unsigned* __restrict__ BtE) {
    int idx = blockIdx.x * 256 + threadIdx.x;
    if (idx >= 64 * EPAIRS) return;
    int c = idx / EPAIRS, p = idx - c * EPAIRS;
    int k0 = 2 * p, k1 = 2 * p + 1;
    float v0 = (k0 < IN_DIM) ? W[k0 * 64 + c] : 0.f;
    float v1 = (k1 < IN_DIM) ? W[k1 * 64 + c] : 0.f;
    BtE[idx] = f2_to_bf2(v0, v1);
}

// ---------- embed via MFMA ----------
__global__ void __launch_bounds__(256)
embed_mfma_k(const float* __restrict__ x, const unsigned* __restrict__ BtE,
             const float* __restrict__ be, const int* __restrict__ ncnt,
             float* __restrict__ h, unsigned* __restrict__ hb,
             unsigned* __restrict__ zb) {
    __shared__ unsigned zsu[64][ELDS];
    __shared__ unsigned btu[64][ELDS];
    int node0 = blockIdx.x * 64;
    int t = threadIdx.x;
    for (int idx = t; idx < 64 * EPAIRS; idx += 256) {
        int r = idx / EPAIRS, p = idx - r * EPAIRS;
        int node = node0 + r;
        unsigned pr = 0u;
        if (node < N_NODES && p < 46) {
            float2 f = *(const float2*)(x + (size_t)node * IN_DIM + 2 * p);
            pr = f2_to_bf2(f.x, f.y);
        }
        zsu[r][p] = pr;
    }
    for (int idx = t; idx < 64 * EPAIRS; idx += 256) {
        int c = idx / EPAIRS, p = idx - c * EPAIRS;
        btu[c][p] = BtE[idx];
    }
    __syncthreads();
    int w = t >> 6, lane = t & 63, row16 = lane & 15, kg = lane >> 4;
    f32x4 acc[4];
#pragma unroll
    for (int n = 0; n < 4; ++n) acc[n] = (f32x4){0.f, 0.f, 0.f, 0.f};
#pragma unroll
    for (int ks = 0; ks < 3; ++ks) {
        int pbase = ks * 16 + kg * 4;
        bf16x8 a = *(const bf16x8*)&zsu[w * 16 + row16][pbase];
#pragma unroll
        for (int n = 0; n < 4; ++n) {
            bf16x8 b = *(const bf16x8*)&btu[n * 16 + row16][pbase];
            acc[n] = __builtin_amdgcn_mfma_f32_16x16x32_bf16(a, b, acc[n], 0, 0, 0);
        }
    }
#pragma unroll
    for (int i = 0; i < 4; ++i) {
        int node = node0 + w * 16 + kg * 4 + i;
        if (node < N_NODES) {
            bool has = ncnt[node] > 0;
#pragma unroll
            for (int n = 0; n < 4; ++n) {
                int d = n * 16 + row16;
                float nv = acc[n][i] + be[d];
                h[node * 64 + d] = nv;
                float other = __shfl_xor(nv, 1);
                if ((d & 1) == 0) {
                    unsigned pr = f2_to_bf2(nv, other);
                    hb[node * 32 + (d >> 1)] = pr;
                    zb[(size_t)node * KPAIRS + (d >> 1)] = has ? pr : 0u;
                }
            }
        }
    }
}

// ---------- hattr -> bf16 padded mirror ----------
__global__ void attrconv_k(const float* __restrict__ hattr, unsigned* __restrict__ hab) {
    int idx = blockIdx.x * 256 + threadIdx.x;
    if (idx >= N_HEDGES * ATTR_PAIRS) return;
    int e = idx / ATTR_PAIRS, p = idx - e * ATTR_PAIRS;
    int d0 = 2 * p, d1 = 2 * p + 1;
    float v0 = hattr[e * ATTR_DIM + d0];
    float v1 = (d1 < ATTR_DIM) ? hattr[e * ATTR_DIM + d1] : 0.f;
    hab[idx] = f2_to_bf2(v0, v1);
}

// ---------- zero rows for guard-free gathers ----------
__global__ void zrow_k(uint2* __restrict__ hbz, uint2* __restrict__ hmz,
                       uint2* __restrict__ habz) {
    int t = threadIdx.x;
    if (t < 16) hbz[t] = make_uint2(0u, 0u);
    else if (t < 32) hmz[t - 16] = make_uint2(0u, 0u);
    else if (t < 41) habz[t - 32] = make_uint2(0u, 0u);
}

// ---------- layer weights -> Bt bf16 [l][c=128][k pairs=96] ----------
__global__ void btpack_k(const float* __restrict__ Wf, const float* __restrict__ Wc,
                         unsigned* __restrict__ Btb) {
    int idx = blockIdx.x * 256 + threadIdx.x;
    if (idx >= N_LAYERS * 128 * KPAIRS) return;
    int l = idx / (128 * KPAIRS);
    int rem = idx - l * 128 * KPAIRS;
    int c = rem / KPAIRS, p = rem - c * KPAIRS;
    int k0 = 2 * p, k1 = 2 * p + 1;
    const float* W = (c < 64) ? (Wf + (size_t)l * MSG_DIM * 64) : (Wc + (size_t)l * MSG_DIM * 64);
    int cc = c & 63;
    float v0 = (k0 < MSG_DIM) ? W[k0 * 64 + cc] : 0.f;
    float v1 = (k1 < MSG_DIM) ? W[k1 * 64 + cc] : 0.f;
    Btb[idx] = f2_to_bf2(v0, v1);
}

// ---------- sort S1 ----------
__global__ void sorthist_k(const int* __restrict__ key, int* __restrict__ hist,
                           int kshift, int NB) {
    __shared__ int cnt[640];
    int blk = blockIdx.x;
    for (int i = threadIdx.x; i < NB; i += 256) cnt[i] = 0;
    __syncthreads();
    int base = blk * IPB;
    int end = min(base + IPB, N_INCID);
    for (int i = base + threadIdx.x; i < end; i += 256)
        atomicAdd(&cnt[key[i] >> kshift], 1);
    __syncthreads();
    for (int i = threadIdx.x; i < NB; i += 256) hist[blk * NB + i] = cnt[i];
}

// ---------- scan with bucket-major remap ----------
__global__ void scanR1_k(const int* __restrict__ in, int* __restrict__ out,
                         int* __restrict__ bsum, int n, int NB) {
    __shared__ int tmp[256];
    int gid = blockIdx.x * 256 + threadIdx.x;
    int v = 0;
    if (gid < n) {
        int bucket = gid / NBLK, blk = gid - bucket * NBLK;
        v = in[blk * NB + bucket];
    }
    tmp[threadIdx.x] = v;
    __syncthreads();
    for (int o = 1; o < 256; o <<= 1) {
        int t = (threadIdx.x >= o) ? tmp[threadIdx.x - o] : 0;
        __syncthreads();
        tmp[threadIdx.x] += t;
        __syncthreads();
    }
    if (gid < n) out[gid] = tmp[threadIdx.x] - v;
    if (threadIdx.x == 255) bsum[blockIdx.x] = tmp[255];
}

__global__ void scan2_k(int* __restrict__ bsum, int nb) {
    __shared__ int tmp[256];
    __shared__ int carry;
    if (threadIdx.x == 0) carry = 0;
    __syncthreads();
    for (int base = 0; base < nb; base += 256) {
        int gid = base + threadIdx.x;
        int v = (gid < nb) ? bsum[gid] : 0;
        tmp[threadIdx.x] = v;
        __syncthreads();
        for (int o = 1; o < 256; o <<= 1) {
            int t = (threadIdx.x >= o) ? tmp[threadIdx.x - o] : 0;
            __syncthreads();
            tmp[threadIdx.x] += t;
            __syncthreads();
        }
        if (gid < nb) bsum[gid] = tmp[threadIdx.x] - v + carry;
        __syncthreads();
        if (threadIdx.x == 0) carry += tmp[255];
        __syncthreads();
    }
}

__global__ void scan3_k(int* __restrict__ out, const int* __restrict__ bsum, int n) {
    int gid = blockIdx.x * 256 + threadIdx.x;
    if (gid < n) out[gid] += bsum[blockIdx.x];
}

// ---------- sort S3: scatter (key low bits | val) packed in 32 bits ----------
__global__ void sortscat_k(const int* __restrict__ key, const int* __restrict__ val,
                           const int* __restrict__ soff, unsigned* __restrict__ stage,
                           int kshift, int NB) {
    __shared__ int cur[640], bas[640];
    int blk = blockIdx.x;
    for (int i = threadIdx.x; i < NB; i += 256) {
        cur[i] = 0;
        bas[i] = soff[i * NBLK + blk];
    }
    __syncthreads();
    int base = blk * IPB;
    int end = min(base + IPB, N_INCID);
    unsigned kmaskbits = (1u << kshift) - 1u;
    for (int i = base + threadIdx.x; i < end; i += 256) {
        int k = key[i], b = k >> kshift;
        int d = bas[b] + atomicAdd(&cur[b], 1);
        stage[d] = (((unsigned)k & kmaskbits) << VALBITS) | (unsigned)val[i];
    }
}

// ---------- sort S4: fine counting-sort within bucket (parallel LDS scan) ----------
__global__ void sortfine_k(const unsigned* __restrict__ stage, const int* __restrict__ soff,
                           int* __restrict__ csr, int* __restrict__ koff,
                           float* __restrict__ krcp, int* __restrict__ kcnt,
                           int kshift, int NB, int NKEYS) {
    __shared__ int cnt[512], off[512], cur[512];
    __shared__ int ts[256];
    int b = blockIdx.x;
    int tid = threadIdx.x;
    int KPB = 1 << kshift;
    int kbase = b << kshift;
    int base = soff[b * NBLK];
    int end = (b == NB - 1) ? N_INCID : soff[(b + 1) * NBLK];
    for (int i = tid; i < KPB; i += 256) cnt[i] = 0;
    __syncthreads();
    for (int i = base + tid; i < end; i += 256)
        atomicAdd(&cnt[stage[i] >> VALBITS], 1);
    __syncthreads();
    int half = KPB >> 1;
    int c0 = 0, c1 = 0;
    if (tid < half) { c0 = cnt[2 * tid]; c1 = cnt[2 * tid + 1]; ts[tid] = c0 + c1; }
    __syncthreads();
    for (int o = 1; o < 256; o <<= 1) {
        int v = (tid >= o && tid < half) ? ts[tid - o] : 0;
        __syncthreads();
        if (tid < half) ts[tid] += v;
        __syncthreads();
    }
    if (tid < half) {
        int ex = ts[tid] - (c0 + c1);
        off[2 * tid] = ex;
        off[2 * tid + 1] = ex + c0;
    }
    __syncthreads();
    for (int k = tid; k < KPB; k += 256) {
        int gk = kbase + k;
        if (gk < NKEYS) {
            koff[gk] = base + off[k];
            krcp[gk] = 1.0f / (float)max(cnt[k], 1);
            kcnt[gk] = cnt[k];
        }
        cur[k] = 0;
    }
    __syncthreads();
    for (int i = base + tid; i < end; i += 256) {
        unsigned it = stage[i];
        int lk = (int)(it >> VALBITS);
        int pos = base + off[lk] + atomicAdd(&cur[lk], 1);
        csr[pos] = (int)(it & ((1u << VALBITS) - 1u));
    }
}

__global__ void sentinel_k(int* __restrict__ eoff, int* __restrict__ noff) {
    if (threadIdx.x == 0) eoff[N_HEDGES] = N_INCID;
    if (threadIdx.x == 1) noff[N_NODES] = N_INCID;
}

// ---------- per-hedge mean: guard-free gather via zero-row, scalar 3-op unpack ----------
__global__ void hmean_k(const int* __restrict__ eoff, const int* __restrict__ csr_en,
                        const uint2* __restrict__ hbv, const float* __restrict__ ercp,
                        uint2* __restrict__ hmv) {
    int idx = blockIdx.x * 256 + threadIdx.x;
    int e = idx >> 5, l = idx & 31;
    if (e >= N_HEDGES) return;
    int sub = l >> 4, q = l & 15;
    int s = eoff[e], t = eoff[e + 1];
    float a0 = 0.f, a1 = 0.f, a2 = 0.f, a3 = 0.f;
    for (int base = s; base < t; base += 32) {
        int cnt = min(32, t - base);
        int myidx = (base + l < t) ? csr_en[base + l] : N_NODES;  // zero row
        for (int j = 0; j < cnt; j += 16) {
            uint2 v[8];
#pragma unroll
            for (int w = 0; w < 8; ++w) {
                int nq = __shfl(myidx, j + 2 * w + sub, 32);
                v[w] = hbv[nq * 16 + q];
            }
#pragma unroll
            for (int w = 0; w < 8; ++w) {
                a0 += u2f(v[w].x << 16);
                a1 += u2f(v[w].x);   // low 16 bits = noise ~2^-9 rel (validated R9)
                a2 += u2f(v[w].y << 16);
                a3 += u2f(v[w].y);
            }
        }
    }
    a0 += __shfl_xor(a0, 16);
    a1 += __shfl_xor(a1, 16);
    a2 += __shfl_xor(a2, 16);
    a3 += __shfl_xor(a3, 16);
    if (sub == 0) {
        float rc = ercp[e];
        hmv[e * 16 + q] = make_uint2(f2_to_bf2(a0 * rc, a1 * rc), f2_to_bf2(a2 * rc, a3 * rc));
    }
}

// ---------- per-node mean of hmean -> zb pairs 32..63 ----------
__global__ void nodeh_k(const int* __restrict__ noff, const int* __restrict__ csr_ne,
                        const uint2* __restrict__ hmv, const float* __restrict__ nrcp,
                        uint2* __restrict__ zbv) {
    int idx = blockIdx.x * 256 + threadIdx.x;
    int n = idx >> 5, l = idx & 31;
    if (n >= N_NODES) return;
    int sub = l >> 4, q = l & 15;
    int s = noff[n], t = noff[n + 1];
    float a0 = 0.f, a1 = 0.f, a2 = 0.f, a3 = 0.f;
    for (int base = s; base < t; base += 32) {
        int cnt = min(32, t - base);
        int myidx = (base + l < t) ? csr_ne[base + l] : N_HEDGES;  // zero row
        for (int j = 0; j < cnt; j += 16) {
            uint2 v[8];
#pragma unroll
            for (int w = 0; w < 8; ++w) {
                int eq = __shfl(myidx, j + 2 * w + sub, 32);
                v[w] = hmv[eq * 16 + q];
            }
#pragma unroll
            for (int w = 0; w < 8; ++w) {
                a0 += u2f(v[w].x << 16);
                a1 += u2f(v[w].x);
                a2 += u2f(v[w].y << 16);
                a3 += u2f(v[w].y);
            }
        }
    }
    a0 += __shfl_xor(a0, 16);
    a1 += __shfl_xor(a1, 16);
    a2 += __shfl_xor(a2, 16);
    a3 += __shfl_xor(a3, 16);
    if (sub == 0) {
        float rc = nrcp[n];
        zbv[(size_t)n * (KPAIRS / 2) + 16 + q] =
            make_uint2(f2_to_bf2(a0 * rc, a1 * rc), f2_to_bf2(a2 * rc, a3 * rc));
    }
}

// ---------- per-node mean of hedge_attr -> zb pairs 64..95 (one-time) ----------
__global__ void nodea_k(const int* __restrict__ noff, const int* __restrict__ csr_ne,
                        const uint2* __restrict__ habv, const float* __restrict__ nrcp,
                        uint2* __restrict__ zbv) {
    int idx = blockIdx.x * 256 + threadIdx.x;
    int n = idx >> 5, l = idx & 31;
    if (n >= N_NODES) return;
    int sub = l >> 4, q = l & 15;
    bool act = (q < ATTR_PAIRS / 2);
    int qa = act ? q : 0;   // inactive lanes load an aliased valid slot; sums discarded
    int s = noff[n], t = noff[n + 1];
    float a0 = 0.f, a1 = 0.f, a2 = 0.f, a3 = 0.f;
    for (int base = s; base < t; base += 32) {
        int cnt = min(32, t - base);
        int myidx = (base + l < t) ? csr_ne[base + l] : N_HEDGES;  // zero row
        for (int j = 0; j < cnt; j += 16) {
            uint2 v[8];
#pragma unroll
            for (int w = 0; w < 8; ++w) {
                int eq = __shfl(myidx, j + 2 * w + sub, 32);
                v[w] = habv[eq * (ATTR_PAIRS / 2) + qa];
            }
#pragma unroll
            for (int w = 0; w < 8; ++w) {
                a0 += u2f(v[w].x << 16);
                a1 += u2f(v[w].x);
                a2 += u2f(v[w].y << 16);
                a3 += u2f(v[w].y);
            }
        }
    }
    a0 += __shfl_xor(a0, 16);
    a1 += __shfl_xor(a1, 16);
    a2 += __shfl_xor(a2, 16);
    a3 += __shfl_xor(a3, 16);
    if (sub == 0) {
        float rc = nrcp[n];
        uint2 pr = act ? make_uint2(f2_to_bf2(a0 * rc, a1 * rc), f2_to_bf2(a2 * rc, a3 * rc))
                       : make_uint2(0u, 0u);
        zbv[(size_t)n * (KPAIRS / 2) + 32 + q] = pr;
    }
}

// ---------- layer GEMM via MFMA; B in registers, A in LDS ----------
__global__ void __launch_bounds__(256)
layer_mfma_k(const unsigned* __restrict__ Btl, const float* __restrict__ bfv,
             const float* __restrict__ bcv, const int* __restrict__ ncnt,
             unsigned* __restrict__ zb, float* __restrict__ h,
             unsigned* __restrict__ hb) {
    __shared__ unsigned zsu[64][ZLDS];
    int node0 = blockIdx.x * 64;
    int t = threadIdx.x;
    int w = t >> 6, lane = t & 63;
    int row16 = lane & 15, kg = lane >> 4;

    uint4 bregF[6], bregC[6];
    {
        const uint4* bv = (const uint4*)Btl;
        int colF = w * 16 + row16;
        int colC = colF + 64;
#pragma unroll
        for (int ks = 0; ks < 6; ++ks) {
            bregF[ks] = bv[colF * 24 + ks * 4 + kg];
            bregC[ks] = bv[colC * 24 + ks * 4 + kg];
        }
    }
    {
        const uint4* zv = (const uint4*)zb;
        for (int idx = t; idx < 64 * 24; idx += 256) {
            int r = idx / 24, p4 = idx - r * 24;
            int node = node0 + r;
            uint4 v = make_uint4(0u, 0u, 0u, 0u);
            if (node < N_NODES) v = zv[(size_t)node * 24 + p4];
            *(uint4*)&zsu[r][p4 * 4] = v;
        }
    }
    __syncthreads();

    f32x4 accF[4], accC[4];
#pragma unroll
    for (int n = 0; n < 4; ++n) {
        accF[n] = (f32x4){0.f, 0.f, 0.f, 0.f};
        accC[n] = (f32x4){0.f, 0.f, 0.f, 0.f};
    }

#pragma unroll
    for (int ks = 0; ks < 6; ++ks) {
        int pbase = ks * 16 + kg * 4;
        bf16x8 bF = *(const bf16x8*)&bregF[ks];
        bf16x8 bC = *(const bf16x8*)&bregC[ks];
#pragma unroll
        for (int rb = 0; rb < 4; ++rb) {
            bf16x8 a = *(const bf16x8*)&zsu[rb * 16 + row16][pbase];
            accF[rb] = __builtin_amdgcn_mfma_f32_16x16x32_bf16(a, bF, accF[rb], 0, 0, 0);
            accC[rb] = __builtin_amdgcn_mfma_f32_16x16x32_bf16(a, bC, accC[rb], 0, 0, 0);
        }
    }

    int d = w * 16 + row16;
    float bfd = bfv[d], bcd = bcv[d];
#pragma unroll
    for (int rb = 0; rb < 4; ++rb) {
#pragma unroll
        for (int i = 0; i < 4; ++i) {
            int node = node0 + rb * 16 + kg * 4 + i;
            if (node < N_NODES) {
                bool has = ncnt[node] > 0;
                float f = accF[rb][i] + bfd;
                float c = accC[rb][i] + bcd;
                float hv = h[node * 64 + d];
                float nv = softplusf(sigmoidf(f) * softplusf(c) + hv);
                h[node * 64 + d] = nv;
                float other = __shfl_xor(nv, 1);
                if ((d & 1) == 0) {
                    unsigned pr = f2_to_bf2(nv, other);
                    hb[node * 32 + (d >> 1)] = pr;
                    zb[(size_t)node * KPAIRS + (d >> 1)] = has ? pr : 0u;
                }
            }
        }
    }
}

// ---------- per-graph boundaries ----------
__global__ void gstart_k(const int* __restrict__ batch, int* __restrict__ gstart) {
    int g = blockIdx.x * 256 + threadIdx.x;
    if (g > N_GRAPHS) return;
    int lo = 0, hi = N_NODES;
    while (lo < hi) {
        int mid = (lo + hi) >> 1;
        if (batch[mid] < g) lo = mid + 1; else hi = mid;
    }
    gstart[g] = lo;
}

// ---------- fused pool + proj + out ----------
__global__ void poolhead_k(const float* __restrict__ h, const int* __restrict__ gstart,
                           const float* __restrict__ Wp, const float* __restrict__ bp,
                           const float* __restrict__ Wo, const float* __restrict__ bo,
                           float* __restrict__ out) {
    __shared__ float partial[4][64];
    __shared__ float pm[64];
    __shared__ float pr[128];
    int g = blockIdx.x, t = threadIdx.x;
    int s = gstart[g], e = gstart[g + 1];
    int w = t >> 6, lane = t & 63;
    float acc = 0.f;
    for (int n = s + w; n < e; n += 4) acc += h[n * 64 + lane];
    partial[w][lane] = acc;
    __syncthreads();
    if (t < 64) {
        float c = fmaxf((float)(e - s), 1.0f);
        pm[t] = (partial[0][t] + partial[1][t] + partial[2][t] + partial[3][t]) / c;
    }
    __syncthreads();
    if (t < 128) {
        float a = bp[t];
#pragma unroll 4
        for (int k = 0; k < 64; ++k) a += pm[k] * Wp[k * HOUT_DIM + t];
        pr[t] = softplusf(a) * Wo[t];
    }
    __syncthreads();
    if (t < 64) {
        float v = pr[t] + pr[t + 64];
        for (int o = 32; o > 0; o >>= 1) v += __shfl_down(v, o);
        if (t == 0) out[g] = v + bo[0];
    }
}

extern "C" void kernel_launch(void* const* d_in, const int* in_sizes, int n_in,
                              void* d_out, int out_size, void* d_ws, size_t ws_size,
                              hipStream_t stream) {
    const float* x       = (const float*)d_in[0];
    const int*   inc_n   = (const int*)d_in[1];
    const int*   inc_e   = (const int*)d_in[2];
    const float* hattr   = (const float*)d_in[3];
    const int*   batch   = (const int*)d_in[4];
    const float* W_embed = (const float*)d_in[5];
    const float* b_embed = (const float*)d_in[6];
    const float* Wf      = (const float*)d_in[7];
    const float* bf      = (const float*)d_in[8];
    const float* Wc      = (const float*)d_in[9];
    const float* bc      = (const float*)d_in[10];
    const float* W_proj  = (const float*)d_in[11];
    const float* b_proj  = (const float*)d_in[12];
    const float* W_out   = (const float*)d_in[13];
    const float* b_out   = (const float*)d_in[14];
    float* out = (float*)d_out;

    char* ws = (char*)d_ws;
    size_t off = 0;
    auto alloc = [&](size_t bytes) {
        void* p = ws + off;
        off = (off + bytes + 255) & ~(size_t)255;
        return p;
    };
    float*    h      = (float*)alloc((size_t)N_NODES * 64 * 4);
    unsigned* hb     = (unsigned*)alloc((size_t)(N_NODES + 1) * 32 * 4);     // +zero row
    unsigned* hmean  = (unsigned*)alloc((size_t)(N_HEDGES + 1) * 32 * 4);    // +zero row; aliases sort staging
    unsigned* zb     = (unsigned*)alloc((size_t)N_NODES * KPAIRS * 4);
    unsigned* hab    = (unsigned*)alloc((size_t)(N_HEDGES + 1) * ATTR_PAIRS * 4);  // +zero row
    unsigned* Btb    = (unsigned*)alloc((size_t)N_LAYERS * 128 * KPAIRS * 4);
    unsigned* BtE    = (unsigned*)alloc((size_t)64 * EPAIRS * 4);
    int*      ncnt   = (int*)alloc((size_t)N_NODES * 4);
    int*      ecnt   = (int*)alloc((size_t)N_HEDGES * 4);
    float*    nrcp   = (float*)alloc((size_t)N_NODES * 4);
    float*    ercp   = (float*)alloc((size_t)N_HEDGES * 4);
    int*      eoff   = (int*)alloc((size_t)(N_HEDGES + 1) * 4);
    int*      noff   = (int*)alloc((size_t)(N_NODES + 1) * 4);
    int*      csr_en = (int*)alloc((size_t)N_INCID * 4);
    int*      csr_ne = (int*)alloc((size_t)N_INCID * 4);
    int*      hist   = (int*)alloc((size_t)NB_E * NBLK * 4);
    int*      soff   = (int*)alloc((size_t)NB_E * NBLK * 4);
    int*      bsum   = (int*)alloc((size_t)2048 * 4);
    int*      gstart = (int*)alloc((size_t)(N_GRAPHS + 1) * 4);
    unsigned* stage  = (unsigned*)hmean;

    // ---- hedge-side sort ----
    {
        int nlog = NB_E * NBLK;
        int nsb = (nlog + 255) / 256;
        sorthist_k<<<NBLK, 256, 0, stream>>>(inc_e, hist, ESHIFT, NB_E);
        scanR1_k<<<nsb, 256, 0, stream>>>(hist, soff, bsum, nlog, NB_E);
        scan2_k<<<1, 256, 0, stream>>>(bsum, nsb);
        scan3_k<<<nsb, 256, 0, stream>>>(soff, bsum, nlog);
        sortscat_k<<<NBLK, 256, 0, stream>>>(inc_e, inc_n, soff, stage, ESHIFT, NB_E);
        sortfine_k<<<NB_E, 256, 0, stream>>>(stage, soff, csr_en, eoff, ercp, ecnt,
                                             ESHIFT, NB_E, N_HEDGES);
    }
    // ---- node-side sort ----
    {
        int nlog = NB_N * NBLK;
        int nsb = (nlog + 255) / 256;
        sorthist_k<<<NBLK, 256, 0, stream>>>(inc_n, hist, NSHIFT, NB_N);
        scanR1_k<<<nsb, 256, 0, stream>>>(hist, soff, bsum, nlog, NB_N);
        scan2_k<<<1, 256, 0, stream>>>(bsum, nsb);
        scan3_k<<<nsb, 256, 0, stream>>>(soff, bsum, nlog);
        sortscat_k<<<NBLK, 256, 0, stream>>>(inc_n, inc_e, soff, stage, NSHIFT, NB_N);
        sortfine_k<<<NB_N, 256, 0, stream>>>(stage, soff, csr_ne, noff, nrcp, ncnt,
                                             NSHIFT, NB_N, N_NODES);
    }
    sentinel_k<<<1, 64, 0, stream>>>(eoff, noff);
    zrow_k<<<1, 64, 0, stream>>>((uint2*)hb + (size_t)N_NODES * 16,
                                 (uint2*)hmean + (size_t)N_HEDGES * 16,
                                 (uint2*)hab + (size_t)N_HEDGES * (ATTR_PAIRS / 2));

    embpack_k<<<(64 * EPAIRS + 255) / 256, 256, 0, stream>>>(W_embed, BtE);
    embed_mfma_k<<<(N_NODES + 63) / 64, 256, 0, stream>>>(x, BtE, b_embed, ncnt, h, hb, zb);
    attrconv_k<<<(N_HEDGES * ATTR_PAIRS + 255) / 256, 256, 0, stream>>>(hattr, hab);
    btpack_k<<<(N_LAYERS * 128 * KPAIRS + 255) / 256, 256, 0, stream>>>(Wf, Wc, Btb);
    nodea_k<<<(N_NODES * 32) / 256, 256, 0, stream>>>(noff, csr_ne, (const uint2*)hab, nrcp,
                                                      (uint2*)zb);

    for (int l = 0; l < N_LAYERS; ++l) {
        hmean_k<<<(N_HEDGES * 32) / 256, 256, 0, stream>>>(eoff, csr_en, (const uint2*)hb, ercp,
                                                           (uint2*)hmean);
        nodeh_k<<<(N_NODES * 32) / 256, 256, 0, stream>>>(noff, csr_ne, (const uint2*)hmean, nrcp,
                                                          (uint2*)zb);
        layer_mfma_k<<<(N_NODES + 63) / 64, 256, 0, stream>>>(Btb + (size_t)l * 128 * KPAIRS,
                                                              bf + l * 64, bc + l * 64,
                                                              ncnt, zb, h, hb);
    }
    gstart_k<<<(N_GRAPHS + 1 + 255) / 256, 256, 0, stream>>>(batch, gstart);
    poolhead_k<<<N_GRAPHS, 256, 0, stream>>>(h, gstart, W_proj, b_proj, W_out, b_out, out);
}

// Round 11
// 637.801 us; speedup vs baseline: 1.1271x; 1.0384x over previous
//
#include <hip/hip_runtime.h>
#include <hip/hip_bf16.h>

#define N_NODES 100000
#define N_INCID 2000000
#define N_HEDGES 300000
#define IN_DIM 92
#define H_DIM 64
#define ATTR_DIM 35
#define ATTR_PAIRS 18
#define HOUT_DIM 128
#define N_GRAPHS 512
#define N_LAYERS 3
#define MSG_DIM 163
#define KPAIRS 96        // layer K padded to 192 bf16 = 96 uint pairs
#define ZLDS 100         // layer LDS row stride in uints
#define EPAIRS 48        // embed K padded to 96 bf16 = 48 pairs
#define ELDS 50          // embed LDS row stride in uints

// sort geometry
#define IPB 8192
#define NBLK 245
#define ESHIFT 9
#define NB_E 586
#define NSHIFT 8
#define NB_N 391
#define VALBITS 21       // N_INCID < 2^21

typedef short bf16x8 __attribute__((ext_vector_type(8)));
typedef float f32x4 __attribute__((ext_vector_type(4)));

__device__ __forceinline__ float softplusf(float x) {
    return fmaxf(x, 0.f) + __logf(1.f + __expf(-fabsf(x)));
}
__device__ __forceinline__ float sigmoidf(float x) {
    return __builtin_amdgcn_rcpf(1.f + __expf(-x));
}
__device__ __forceinline__ float u2f(unsigned u) {
    union { unsigned u; float f; } x; x.u = u; return x.f;
}
__device__ __forceinline__ unsigned f2_to_bf2(float x, float y) {
    union { float f; unsigned u; } a, b;
    a.f = x; b.f = y;
    unsigned lo = (a.u + 0x7fffu + ((a.u >> 16) & 1u)) >> 16;
    unsigned hi = ((b.u + 0x7fffu + ((b.u >> 16) & 1u)) >> 16) << 16;
    return lo | hi;
}

// ---------- W_embed -> bf16 Bt [c=64][p=48] ----------
__global__ void embpack_k(const float* __restrict__ W, unsigned* __restrict__ BtE) {
    int idx = blockIdx.x * 256 + threadIdx.x;
    if (idx >= 64 * EPAIRS) return;
    int c = idx / EPAIRS, p = idx - c * EPAIRS;
    int k0 = 2 * p, k1 = 2 * p + 1;
    float v0 = (k0 < IN_DIM) ? W[k0 * 64 + c] : 0.f;
    float v1 = (k1 < IN_DIM) ? W[k1 * 64 + c] : 0.f;
    BtE[idx] = f2_to_bf2(v0, v1);
}

// ---------- embed via MFMA ----------
__global__ void __launch_bounds__(256)
embed_mfma_k(const float* __restrict__ x, const unsigned* __restrict__ BtE,
             const float* __restrict__ be, const int* __restrict__ ncnt,
             float* __restrict__ h, unsigned* __restrict__ hb,
             unsigned* __restrict__ zb) {
    __shared__ unsigned zsu[64][ELDS];
    __shared__ unsigned btu[64][ELDS];
    int node0 = blockIdx.x * 64;
    int t = threadIdx.x;
    for (int idx = t; idx < 64 * EPAIRS; idx += 256) {
        int r = idx / EPAIRS, p = idx - r * EPAIRS;
        int node = node0 + r;
        unsigned pr = 0u;
        if (node < N_NODES && p < 46) {
            float2 f = *(const float2*)(x + (size_t)node * IN_DIM + 2 * p);
            pr = f2_to_bf2(f.x, f.y);
        }
        zsu[r][p] = pr;
    }
    for (int idx = t; idx < 64 * EPAIRS; idx += 256) {
        int c = idx / EPAIRS, p = idx - c * EPAIRS;
        btu[c][p] = BtE[idx];
    }
    __syncthreads();
    int w = t >> 6, lane = t & 63, row16 = lane & 15, kg = lane >> 4;
    f32x4 acc[4];
#pragma unroll
    for (int n = 0; n < 4; ++n) acc[n] = (f32x4){0.f, 0.f, 0.f, 0.f};
#pragma unroll
    for (int ks = 0; ks < 3; ++ks) {
        int pbase = ks * 16 + kg * 4;
        bf16x8 a = *(const bf16x8*)&zsu[w * 16 + row16][pbase];
#pragma unroll
        for (int n = 0; n < 4; ++n) {
            bf16x8 b = *(const bf16x8*)&btu[n * 16 + row16][pbase];
            acc[n] = __builtin_amdgcn_mfma_f32_16x16x32_bf16(a, b, acc[n], 0, 0, 0);
        }
    }
#pragma unroll
    for (int i = 0; i < 4; ++i) {
        int node = node0 + w * 16 + kg * 4 + i;
        if (node < N_NODES) {
            bool has = ncnt[node] > 0;
#pragma unroll
            for (int n = 0; n < 4; ++n) {
                int d = n * 16 + row16;
                float nv = acc[n][i] + be[d];
                h[node * 64 + d] = nv;
                float other = __shfl_xor(nv, 1);
                if ((d & 1) == 0) {
                    unsigned pr = f2_to_bf2(nv, other);
                    hb[node * 32 + (d >> 1)] = pr;
                    zb[(size_t)node * KPAIRS + (d >> 1)] = has ? pr : 0u;
                }
            }
        }
    }
}

// ---------- hattr -> bf16 padded mirror ----------
__global__ void attrconv_k(const float* __restrict__ hattr, unsigned* __restrict__ hab) {
    int idx = blockIdx.x * 256 + threadIdx.x;
    if (idx >= N_HEDGES * ATTR_PAIRS) return;
    int e = idx / ATTR_PAIRS, p = idx - e * ATTR_PAIRS;
    int d0 = 2 * p, d1 = 2 * p + 1;
    float v0 = hattr[e * ATTR_DIM + d0];
    float v1 = (d1 < ATTR_DIM) ? hattr[e * ATTR_DIM + d1] : 0.f;
    hab[idx] = f2_to_bf2(v0, v1);
}

// ---------- layer weights -> Bt bf16 [l][c=128][k pairs=96] ----------
__global__ void btpack_k(const float* __restrict__ Wf, const float* __restrict__ Wc,
                         unsigned* __restrict__ Btb) {
    int idx = blockIdx.x * 256 + threadIdx.x;
    if (idx >= N_LAYERS * 128 * KPAIRS) return;
    int l = idx / (128 * KPAIRS);
    int rem = idx - l * 128 * KPAIRS;
    int c = rem / KPAIRS, p = rem - c * KPAIRS;
    int k0 = 2 * p, k1 = 2 * p + 1;
    const float* W = (c < 64) ? (Wf + (size_t)l * MSG_DIM * 64) : (Wc + (size_t)l * MSG_DIM * 64);
    int cc = c & 63;
    float v0 = (k0 < MSG_DIM) ? W[k0 * 64 + cc] : 0.f;
    float v1 = (k1 < MSG_DIM) ? W[k1 * 64 + cc] : 0.f;
    Btb[idx] = f2_to_bf2(v0, v1);
}

// ---------- sort S1 ----------
__global__ void sorthist_k(const int* __restrict__ key, int* __restrict__ hist,
                           int kshift, int NB) {
    __shared__ int cnt[640];
    int blk = blockIdx.x;
    for (int i = threadIdx.x; i < NB; i += 256) cnt[i] = 0;
    __syncthreads();
    int base = blk * IPB;
    int end = min(base + IPB, N_INCID);
    for (int i = base + threadIdx.x; i < end; i += 256)
        atomicAdd(&cnt[key[i] >> kshift], 1);
    __syncthreads();
    for (int i = threadIdx.x; i < NB; i += 256) hist[blk * NB + i] = cnt[i];
}

// ---------- scan with bucket-major remap ----------
__global__ void scanR1_k(const int* __restrict__ in, int* __restrict__ out,
                         int* __restrict__ bsum, int n, int NB) {
    __shared__ int tmp[256];
    int gid = blockIdx.x * 256 + threadIdx.x;
    int v = 0;
    if (gid < n) {
        int bucket = gid / NBLK, blk = gid - bucket * NBLK;
        v = in[blk * NB + bucket];
    }
    tmp[threadIdx.x] = v;
    __syncthreads();
    for (int o = 1; o < 256; o <<= 1) {
        int t = (threadIdx.x >= o) ? tmp[threadIdx.x - o] : 0;
        __syncthreads();
        tmp[threadIdx.x] += t;
        __syncthreads();
    }
    if (gid < n) out[gid] = tmp[threadIdx.x] - v;
    if (threadIdx.x == 255) bsum[blockIdx.x] = tmp[255];
}

__global__ void scan2_k(int* __restrict__ bsum, int nb) {
    __shared__ int tmp[256];
    __shared__ int carry;
    if (threadIdx.x == 0) carry = 0;
    __syncthreads();
    for (int base = 0; base < nb; base += 256) {
        int gid = base + threadIdx.x;
        int v = (gid < nb) ? bsum[gid] : 0;
        tmp[threadIdx.x] = v;
        __syncthreads();
        for (int o = 1; o < 256; o <<= 1) {
            int t = (threadIdx.x >= o) ? tmp[threadIdx.x - o] : 0;
            __syncthreads();
            tmp[threadIdx.x] += t;
            __syncthreads();
        }
        if (gid < nb) bsum[gid] = tmp[threadIdx.x] - v + carry;
        __syncthreads();
        if (threadIdx.x == 0) carry += tmp[255];
        __syncthreads();
    }
}

__global__ void scan3_k(int* __restrict__ out, const int* __restrict__ bsum, int n) {
    int gid = blockIdx.x * 256 + threadIdx.x;
    if (gid < n) out[gid] += bsum[blockIdx.x];
}

// ---------- sort S3: scatter (key low bits | val) packed in 32 bits ----------
__global__ void sortscat_k(const int* __restrict__ key, const int* __restrict__ val,
                           const int* __restrict__ soff, unsigned* __restrict__ stage,
                           int kshift, int NB) {
    __shared__ int cur[640], bas[640];
    int blk = blockIdx.x;
    for (int i = threadIdx.x; i < NB; i += 256) {
        cur[i] = 0;
        bas[i] = soff[i * NBLK + blk];
    }
    __syncthreads();
    int base = blk * IPB;
    int end = min(base + IPB, N_INCID);
    unsigned kmaskbits = (1u << kshift) - 1u;
    for (int i = base + threadIdx.x; i < end; i += 256) {
        int k = key[i], b = k >> kshift;
        int d = bas[b] + atomicAdd(&cur[b], 1);
        stage[d] = (((unsigned)k & kmaskbits) << VALBITS) | (unsigned)val[i];
    }
}

// ---------- sort S4: fine counting-sort within bucket (parallel LDS scan) ----------
__global__ void sortfine_k(const unsigned* __restrict__ stage, const int* __restrict__ soff,
                           int* __restrict__ csr, int* __restrict__ koff,
                           float* __restrict__ krcp, int* __restrict__ kcnt,
                           int kshift, int NB, int NKEYS) {
    __shared__ int cnt[512], off[512], cur[512];
    __shared__ int ts[256];
    int b = blockIdx.x;
    int tid = threadIdx.x;
    int KPB = 1 << kshift;
    int kbase = b << kshift;
    int base = soff[b * NBLK];
    int end = (b == NB - 1) ? N_INCID : soff[(b + 1) * NBLK];
    for (int i = tid; i < KPB; i += 256) cnt[i] = 0;
    __syncthreads();
    for (int i = base + tid; i < end; i += 256)
        atomicAdd(&cnt[stage[i] >> VALBITS], 1);
    __syncthreads();
    int half = KPB >> 1;
    int c0 = 0, c1 = 0;
    if (tid < half) { c0 = cnt[2 * tid]; c1 = cnt[2 * tid + 1]; ts[tid] = c0 + c1; }
    __syncthreads();
    for (int o = 1; o < 256; o <<= 1) {
        int v = (tid >= o && tid < half) ? ts[tid - o] : 0;
        __syncthreads();
        if (tid < half) ts[tid] += v;
        __syncthreads();
    }
    if (tid < half) {
        int ex = ts[tid] - (c0 + c1);
        off[2 * tid] = ex;
        off[2 * tid + 1] = ex + c0;
    }
    __syncthreads();
    for (int k = tid; k < KPB; k += 256) {
        int gk = kbase + k;
        if (gk < NKEYS) {
            koff[gk] = base + off[k];
            krcp[gk] = 1.0f / (float)max(cnt[k], 1);
            kcnt[gk] = cnt[k];
        }
        cur[k] = 0;
    }
    __syncthreads();
    for (int i = base + tid; i < end; i += 256) {
        unsigned it = stage[i];
        int lk = (int)(it >> VALBITS);
        int pos = base + off[lk] + atomicAdd(&cur[lk], 1);
        csr[pos] = (int)(it & ((1u << VALBITS) - 1u));
    }
}

__global__ void sentinel_k(int* __restrict__ eoff, int* __restrict__ noff) {
    if (threadIdx.x == 0) eoff[N_HEDGES] = N_INCID;
    if (threadIdx.x == 1) noff[N_NODES] = N_INCID;
}

// ---------- per-hedge mean: uint4/lane (8 lanes/row, 4 member slots), flights of 4 ----------
__global__ void hmean_k(const int* __restrict__ eoff, const int* __restrict__ csr_en,
                        const uint4* __restrict__ hbv4, const float* __restrict__ ercp,
                        uint4* __restrict__ hmv4) {
    int idx = blockIdx.x * 256 + threadIdx.x;
    int e = idx >> 5, l = idx & 31;
    if (e >= N_HEDGES) return;
    int sub = l >> 3, q = l & 7;
    int s = eoff[e], t = eoff[e + 1];
    float a0 = 0, a1 = 0, a2 = 0, a3 = 0, a4 = 0, a5 = 0, a6 = 0, a7 = 0;
    for (int base = s; base < t; base += 32) {
        int cnt = min(32, t - base);
        int myidx = (base + l < t) ? csr_en[base + l] : 0;
        for (int j = 0; j < cnt; j += 16) {
            uint4 v[4];
#pragma unroll
            for (int w = 0; w < 4; ++w) {
                int mem = j + 4 * w + sub;
                int nq = __shfl(myidx, mem, 32);
                v[w] = (mem < cnt) ? hbv4[nq * 8 + q] : make_uint4(0u, 0u, 0u, 0u);
            }
#pragma unroll
            for (int w = 0; w < 4; ++w) {
                a0 += u2f(v[w].x << 16); a1 += u2f(v[w].x);
                a2 += u2f(v[w].y << 16); a3 += u2f(v[w].y);
                a4 += u2f(v[w].z << 16); a5 += u2f(v[w].z);
                a6 += u2f(v[w].w << 16); a7 += u2f(v[w].w);
            }
        }
    }
    a0 += __shfl_xor(a0, 8); a0 += __shfl_xor(a0, 16);
    a1 += __shfl_xor(a1, 8); a1 += __shfl_xor(a1, 16);
    a2 += __shfl_xor(a2, 8); a2 += __shfl_xor(a2, 16);
    a3 += __shfl_xor(a3, 8); a3 += __shfl_xor(a3, 16);
    a4 += __shfl_xor(a4, 8); a4 += __shfl_xor(a4, 16);
    a5 += __shfl_xor(a5, 8); a5 += __shfl_xor(a5, 16);
    a6 += __shfl_xor(a6, 8); a6 += __shfl_xor(a6, 16);
    a7 += __shfl_xor(a7, 8); a7 += __shfl_xor(a7, 16);
    if (sub == 0) {
        float rc = ercp[e];
        hmv4[e * 8 + q] = make_uint4(f2_to_bf2(a0 * rc, a1 * rc), f2_to_bf2(a2 * rc, a3 * rc),
                                     f2_to_bf2(a4 * rc, a5 * rc), f2_to_bf2(a6 * rc, a7 * rc));
    }
}

// ---------- per-node mean of hmean -> zb uint4 slots 8..15 ----------
__global__ void nodeh_k(const int* __restrict__ noff, const int* __restrict__ csr_ne,
                        const uint4* __restrict__ hmv4, const float* __restrict__ nrcp,
                        uint4* __restrict__ zbv4) {
    int idx = blockIdx.x * 256 + threadIdx.x;
    int n = idx >> 5, l = idx & 31;
    if (n >= N_NODES) return;
    int sub = l >> 3, q = l & 7;
    int s = noff[n], t = noff[n + 1];
    float a0 = 0, a1 = 0, a2 = 0, a3 = 0, a4 = 0, a5 = 0, a6 = 0, a7 = 0;
    for (int base = s; base < t; base += 32) {
        int cnt = min(32, t - base);
        int myidx = (base + l < t) ? csr_ne[base + l] : 0;
        for (int j = 0; j < cnt; j += 16) {
            uint4 v[4];
#pragma unroll
            for (int w = 0; w < 4; ++w) {
                int mem = j + 4 * w + sub;
                int eq = __shfl(myidx, mem, 32);
                v[w] = (mem < cnt) ? hmv4[eq * 8 + q] : make_uint4(0u, 0u, 0u, 0u);
            }
#pragma unroll
            for (int w = 0; w < 4; ++w) {
                a0 += u2f(v[w].x << 16); a1 += u2f(v[w].x);
                a2 += u2f(v[w].y << 16); a3 += u2f(v[w].y);
                a4 += u2f(v[w].z << 16); a5 += u2f(v[w].z);
                a6 += u2f(v[w].w << 16); a7 += u2f(v[w].w);
            }
        }
    }
    a0 += __shfl_xor(a0, 8); a0 += __shfl_xor(a0, 16);
    a1 += __shfl_xor(a1, 8); a1 += __shfl_xor(a1, 16);
    a2 += __shfl_xor(a2, 8); a2 += __shfl_xor(a2, 16);
    a3 += __shfl_xor(a3, 8); a3 += __shfl_xor(a3, 16);
    a4 += __shfl_xor(a4, 8); a4 += __shfl_xor(a4, 16);
    a5 += __shfl_xor(a5, 8); a5 += __shfl_xor(a5, 16);
    a6 += __shfl_xor(a6, 8); a6 += __shfl_xor(a6, 16);
    a7 += __shfl_xor(a7, 8); a7 += __shfl_xor(a7, 16);
    if (sub == 0) {
        float rc = nrcp[n];
        zbv4[(size_t)n * 24 + 8 + q] =
            make_uint4(f2_to_bf2(a0 * rc, a1 * rc), f2_to_bf2(a2 * rc, a3 * rc),
                       f2_to_bf2(a4 * rc, a5 * rc), f2_to_bf2(a6 * rc, a7 * rc));
    }
}

// ---------- per-node mean of hedge_attr -> zb pairs 64..95 (one-time; uint2 guarded) ----------
__global__ void nodea_k(const int* __restrict__ noff, const int* __restrict__ csr_ne,
                        const uint2* __restrict__ habv, const float* __restrict__ nrcp,
                        uint2* __restrict__ zbv) {
    int idx = blockIdx.x * 256 + threadIdx.x;
    int n = idx >> 5, l = idx & 31;
    if (n >= N_NODES) return;
    int sub = l >> 4, q = l & 15;
    bool act = (q < ATTR_PAIRS / 2);
    int s = noff[n], t = noff[n + 1];
    float a0 = 0.f, a1 = 0.f, a2 = 0.f, a3 = 0.f;
    for (int base = s; base < t; base += 32) {
        int cnt = min(32, t - base);
        int myidx = (base + l < t) ? csr_ne[base + l] : 0;
        for (int j = 0; j < cnt; j += 16) {
            uint2 v[8];
#pragma unroll
            for (int w = 0; w < 8; ++w) {
                int mem = j + 2 * w + sub;
                int eq = __shfl(myidx, mem, 32);
                v[w] = (act && mem < cnt) ? habv[eq * (ATTR_PAIRS / 2) + q] : make_uint2(0u, 0u);
            }
#pragma unroll
            for (int w = 0; w < 8; ++w) {
                a0 += u2f(v[w].x << 16); a1 += u2f(v[w].x);
                a2 += u2f(v[w].y << 16); a3 += u2f(v[w].y);
            }
        }
    }
    a0 += __shfl_xor(a0, 16);
    a1 += __shfl_xor(a1, 16);
    a2 += __shfl_xor(a2, 16);
    a3 += __shfl_xor(a3, 16);
    if (sub == 0) {
        float rc = nrcp[n];
        uint2 pr = act ? make_uint2(f2_to_bf2(a0 * rc, a1 * rc), f2_to_bf2(a2 * rc, a3 * rc))
                       : make_uint2(0u, 0u);
        zbv[(size_t)n * (KPAIRS / 2) + 32 + q] = pr;
    }
}

// ---------- layer GEMM via MFMA; B in registers, A in LDS ----------
__global__ void __launch_bounds__(256)
layer_mfma_k(const unsigned* __restrict__ Btl, const float* __restrict__ bfv,
             const float* __restrict__ bcv, const int* __restrict__ ncnt,
             unsigned* __restrict__ zb, float* __restrict__ h,
             unsigned* __restrict__ hb) {
    __shared__ unsigned zsu[64][ZLDS];
    int node0 = blockIdx.x * 64;
    int t = threadIdx.x;
    int w = t >> 6, lane = t & 63;
    int row16 = lane & 15, kg = lane >> 4;

    uint4 bregF[6], bregC[6];
    {
        const uint4* bv = (const uint4*)Btl;
        int colF = w * 16 + row16;
        int colC = colF + 64;
#pragma unroll
        for (int ks = 0; ks < 6; ++ks) {
            bregF[ks] = bv[colF * 24 + ks * 4 + kg];
            bregC[ks] = bv[colC * 24 + ks * 4 + kg];
        }
    }
    {
        const uint4* zv = (const uint4*)zb;
        for (int idx = t; idx < 64 * 24; idx += 256) {
            int r = idx / 24, p4 = idx - r * 24;
            int node = node0 + r;
            uint4 v = make_uint4(0u, 0u, 0u, 0u);
            if (node < N_NODES) v = zv[(size_t)node * 24 + p4];
            *(uint4*)&zsu[r][p4 * 4] = v;
        }
    }
    __syncthreads();

    f32x4 accF[4], accC[4];
#pragma unroll
    for (int n = 0; n < 4; ++n) {
        accF[n] = (f32x4){0.f, 0.f, 0.f, 0.f};
        accC[n] = (f32x4){0.f, 0.f, 0.f, 0.f};
    }

#pragma unroll
    for (int ks = 0; ks < 6; ++ks) {
        int pbase = ks * 16 + kg * 4;
        bf16x8 bF = *(const bf16x8*)&bregF[ks];
        bf16x8 bC = *(const bf16x8*)&bregC[ks];
#pragma unroll
        for (int rb = 0; rb < 4; ++rb) {
            bf16x8 a = *(const bf16x8*)&zsu[rb * 16 + row16][pbase];
            accF[rb] = __builtin_amdgcn_mfma_f32_16x16x32_bf16(a, bF, accF[rb], 0, 0, 0);
            accC[rb] = __builtin_amdgcn_mfma_f32_16x16x32_bf16(a, bC, accC[rb], 0, 0, 0);
        }
    }

    int d = w * 16 + row16;
    float bfd = bfv[d], bcd = bcv[d];
#pragma unroll
    for (int rb = 0; rb < 4; ++rb) {
#pragma unroll
        for (int i = 0; i < 4; ++i) {
            int node = node0 + rb * 16 + kg * 4 + i;
            if (node < N_NODES) {
                bool has = ncnt[node] > 0;
                float f = accF[rb][i] + bfd;
                float c = accC[rb][i] + bcd;
                float hv = h[node * 64 + d];
                float nv = softplusf(sigmoidf(f) * softplusf(c) + hv);
                h[node * 64 + d] = nv;
                float other = __shfl_xor(nv, 1);
                if ((d & 1) == 0) {
                    unsigned pr = f2_to_bf2(nv, other);
                    hb[node * 32 + (d >> 1)] = pr;
                    zb[(size_t)node * KPAIRS + (d >> 1)] = has ? pr : 0u;
                }
            }
        }
    }
}

// ---------- per-graph boundaries ----------
__global__ void gstart_k(const int* __restrict__ batch, int* __restrict__ gstart) {
    int g = blockIdx.x * 256 + threadIdx.x;
    if (g > N_GRAPHS) return;
    int lo = 0, hi = N_NODES;
    while (lo < hi) {
        int mid = (lo + hi) >> 1;
        if (batch[mid] < g) lo = mid + 1; else hi = mid;
    }
    gstart[g] = lo;
}

// ---------- fused pool + proj + out ----------
__global__ void poolhead_k(const float* __restrict__ h, const int* __restrict__ gstart,
                           const float* __restrict__ Wp, const float* __restrict__ bp,
                           const float* __restrict__ Wo, const float* __restrict__ bo,
                           float* __restrict__ out) {
    __shared__ float partial[4][64];
    __shared__ float pm[64];
    __shared__ float pr[128];
    int g = blockIdx.x, t = threadIdx.x;
    int s = gstart[g], e = gstart[g + 1];
    int w = t >> 6, lane = t & 63;
    float acc = 0.f;
    for (int n = s + w; n < e; n += 4) acc += h[n * 64 + lane];
    partial[w][lane] = acc;
    __syncthreads();
    if (t < 64) {
        float c = fmaxf((float)(e - s), 1.0f);
        pm[t] = (partial[0][t] + partial[1][t] + partial[2][t] + partial[3][t]) / c;
    }
    __syncthreads();
    if (t < 128) {
        float a = bp[t];
#pragma unroll 4
        for (int k = 0; k < 64; ++k) a += pm[k] * Wp[k * HOUT_DIM + t];
        pr[t] = softplusf(a) * Wo[t];
    }
    __syncthreads();
    if (t < 64) {
        float v = pr[t] + pr[t + 64];
        for (int o = 32; o > 0; o >>= 1) v += __shfl_down(v, o);
        if (t == 0) out[g] = v + bo[0];
    }
}

extern "C" void kernel_launch(void* const* d_in, const int* in_sizes, int n_in,
                              void* d_out, int out_size, void* d_ws, size_t ws_size,
                              hipStream_t stream) {
    const float* x       = (const float*)d_in[0];
    const int*   inc_n   = (const int*)d_in[1];
    const int*   inc_e   = (const int*)d_in[2];
    const float* hattr   = (const float*)d_in[3];
    const int*   batch   = (const int*)d_in[4];
    const float* W_embed = (const float*)d_in[5];
    const float* b_embed = (const float*)d_in[6];
    const float* Wf      = (const float*)d_in[7];
    const float* bf      = (const float*)d_in[8];
    const float* Wc      = (const float*)d_in[9];
    const float* bc      = (const float*)d_in[10];
    const float* W_proj  = (const float*)d_in[11];
    const float* b_proj  = (const float*)d_in[12];
    const float* W_out   = (const float*)d_in[13];
    const float* b_out   = (const float*)d_in[14];
    float* out = (float*)d_out;

    char* ws = (char*)d_ws;
    size_t off = 0;
    auto alloc = [&](size_t bytes) {
        void* p = ws + off;
        off = (off + bytes + 255) & ~(size_t)255;
        return p;
    };
    float*    h      = (float*)alloc((size_t)N_NODES * 64 * 4);
    unsigned* hb     = (unsigned*)alloc((size_t)N_NODES * 32 * 4);
    unsigned* hmean  = (unsigned*)alloc((size_t)N_HEDGES * 32 * 4);  // aliases sort staging
    unsigned* zb     = (unsigned*)alloc((size_t)N_NODES * KPAIRS * 4);
    unsigned* hab    = (unsigned*)alloc((size_t)N_HEDGES * ATTR_PAIRS * 4);
    unsigned* Btb    = (unsigned*)alloc((size_t)N_LAYERS * 128 * KPAIRS * 4);
    unsigned* BtE    = (unsigned*)alloc((size_t)64 * EPAIRS * 4);
    int*      ncnt   = (int*)alloc((size_t)N_NODES * 4);
    int*      ecnt   = (int*)alloc((size_t)N_HEDGES * 4);
    float*    nrcp   = (float*)alloc((size_t)N_NODES * 4);
    float*    ercp   = (float*)alloc((size_t)N_HEDGES * 4);
    int*      eoff   = (int*)alloc((size_t)(N_HEDGES + 1) * 4);
    int*      noff   = (int*)alloc((size_t)(N_NODES + 1) * 4);
    int*      csr_en = (int*)alloc((size_t)N_INCID * 4);
    int*      csr_ne = (int*)alloc((size_t)N_INCID * 4);
    int*      hist   = (int*)alloc((size_t)NB_E * NBLK * 4);
    int*      soff   = (int*)alloc((size_t)NB_E * NBLK * 4);
    int*      bsum   = (int*)alloc((size_t)2048 * 4);
    int*      gstart = (int*)alloc((size_t)(N_GRAPHS + 1) * 4);
    unsigned* stage  = (unsigned*)hmean;

    // ---- hedge-side sort ----
    {
        int nlog = NB_E * NBLK;
        int nsb = (nlog + 255) / 256;
        sorthist_k<<<NBLK, 256, 0, stream>>>(inc_e, hist, ESHIFT, NB_E);
        scanR1_k<<<nsb, 256, 0, stream>>>(hist, soff, bsum, nlog, NB_E);
        scan2_k<<<1, 256, 0, stream>>>(bsum, nsb);
        scan3_k<<<nsb, 256, 0, stream>>>(soff, bsum, nlog);
        sortscat_k<<<NBLK, 256, 0, stream>>>(inc_e, inc_n, soff, stage, ESHIFT, NB_E);
        sortfine_k<<<NB_E, 256, 0, stream>>>(stage, soff, csr_en, eoff, ercp, ecnt,
                                             ESHIFT, NB_E, N_HEDGES);
    }
    // ---- node-side sort ----
    {
        int nlog = NB_N * NBLK;
        int nsb = (nlog + 255) / 256;
        sorthist_k<<<NBLK, 256, 0, stream>>>(inc_n, hist, NSHIFT, NB_N);
        scanR1_k<<<nsb, 256, 0, stream>>>(hist, soff, bsum, nlog, NB_N);
        scan2_k<<<1, 256, 0, stream>>>(bsum, nsb);
        scan3_k<<<nsb, 256, 0, stream>>>(soff, bsum, nlog);
        sortscat_k<<<NBLK, 256, 0, stream>>>(inc_n, inc_e, soff, stage, NSHIFT, NB_N);
        sortfine_k<<<NB_N, 256, 0, stream>>>(stage, soff, csr_ne, noff, nrcp, ncnt,
                                             NSHIFT, NB_N, N_NODES);
    }
    sentinel_k<<<1, 64, 0, stream>>>(eoff, noff);

    embpack_k<<<(64 * EPAIRS + 255) / 256, 256, 0, stream>>>(W_embed, BtE);
    embed_mfma_k<<<(N_NODES + 63) / 64, 256, 0, stream>>>(x, BtE, b_embed, ncnt, h, hb, zb);
    attrconv_k<<<(N_HEDGES * ATTR_PAIRS + 255) / 256, 256, 0, stream>>>(hattr, hab);
    btpack_k<<<(N_LAYERS * 128 * KPAIRS + 255) / 256, 256, 0, stream>>>(Wf, Wc, Btb);
    nodea_k<<<(N_NODES * 32) / 256, 256, 0, stream>>>(noff, csr_ne, (const uint2*)hab, nrcp,
                                                      (uint2*)zb);

    for (int l = 0; l < N_LAYERS; ++l) {
        hmean_k<<<(N_HEDGES * 32) / 256, 256, 0, stream>>>(eoff, csr_en, (const uint4*)hb, ercp,
                                                           (uint4*)hmean);
        nodeh_k<<<(N_NODES * 32) / 256, 256, 0, stream>>>(noff, csr_ne, (const uint4*)hmean, nrcp,
                                                          (uint4*)zb);
        layer_mfma_k<<<(N_NODES + 63) / 64, 256, 0, stream>>>(Btb + (size_t)l * 128 * KPAIRS,
                                                              bf + l * 64, bc + l * 64,
                                                              ncnt, zb, h, hb);
    }
    gstart_k<<<(N_GRAPHS + 1 + 255) / 256, 256, 0, stream>>>(batch, gstart);
    poolhead_k<<<N_GRAPHS, 256, 0, stream>>>(h, gstart, W_proj, b_proj, W_out, b_out, out);
}

// Round 12
// 592.184 us; speedup vs baseline: 1.2139x; 1.0770x over previous
//
#include <hip/hip_runtime.h>
#include <hip/hip_bf16.h>

#define N_NODES 100000
#define N_INCID 2000000
#define N_HEDGES 300000
#define IN_DIM 92
#define H_DIM 64
#define ATTR_DIM 35
#define ATTR_PAIRS 18
#define HOUT_DIM 128
#define N_GRAPHS 512
#define N_LAYERS 3
#define MSG_DIM 163
#define KPAIRS 96        // layer K padded to 192 bf16 = 96 uint pairs
#define ZLDS 100         // layer LDS row stride in uints
#define EPAIRS 48        // embed K padded to 96 bf16 = 48 pairs
#define ELDS 50          // embed LDS row stride in uints

// sort geometry
#define IPB 8192
#define NBLK 245
#define ESHIFT 9
#define NB_E 586
#define NSHIFT 8
#define NB_N 391
#define VALBITS 21       // ids < 2^21

typedef short bf16x8 __attribute__((ext_vector_type(8)));
typedef float f32x4 __attribute__((ext_vector_type(4)));

__device__ __forceinline__ float softplusf(float x) {
    return fmaxf(x, 0.f) + __logf(1.f + __expf(-fabsf(x)));
}
__device__ __forceinline__ float sigmoidf(float x) {
    return __builtin_amdgcn_rcpf(1.f + __expf(-x));
}
__device__ __forceinline__ float u2f(unsigned u) {
    union { unsigned u; float f; } x; x.u = u; return x.f;
}
__device__ __forceinline__ unsigned f2_to_bf2(float x, float y) {
    union { float f; unsigned u; } a, b;
    a.f = x; b.f = y;
    unsigned lo = (a.u + 0x7fffu + ((a.u >> 16) & 1u)) >> 16;
    unsigned hi = ((b.u + 0x7fffu + ((b.u >> 16) & 1u)) >> 16) << 16;
    return lo | hi;
}

// ---------- W_embed -> bf16 Bt [c=64][p=48] ----------
__global__ void embpack_k(const float* __restrict__ W, unsigned* __restrict__ BtE) {
    int idx = blockIdx.x * 256 + threadIdx.x;
    if (idx >= 64 * EPAIRS) return;
    int c = idx / EPAIRS, p = idx - c * EPAIRS;
    int k0 = 2 * p, k1 = 2 * p + 1;
    float v0 = (k0 < IN_DIM) ? W[k0 * 64 + c] : 0.f;
    float v1 = (k1 < IN_DIM) ? W[k1 * 64 + c] : 0.f;
    BtE[idx] = f2_to_bf2(v0, v1);
}

// ---------- embed via MFMA ----------
__global__ void __launch_bounds__(256)
embed_mfma_k(const float* __restrict__ x, const unsigned* __restrict__ BtE,
             const float* __restrict__ be, const int* __restrict__ ncnt,
             float* __restrict__ h, unsigned* __restrict__ hb,
             unsigned* __restrict__ zb) {
    __shared__ unsigned zsu[64][ELDS];
    __shared__ unsigned btu[64][ELDS];
    int node0 = blockIdx.x * 64;
    int t = threadIdx.x;
    for (int idx = t; idx < 64 * EPAIRS; idx += 256) {
        int r = idx / EPAIRS, p = idx - r * EPAIRS;
        int node = node0 + r;
        unsigned pr = 0u;
        if (node < N_NODES && p < 46) {
            float2 f = *(const float2*)(x + (size_t)node * IN_DIM + 2 * p);
            pr = f2_to_bf2(f.x, f.y);
        }
        zsu[r][p] = pr;
    }
    for (int idx = t; idx < 64 * EPAIRS; idx += 256) {
        int c = idx / EPAIRS, p = idx - c * EPAIRS;
        btu[c][p] = BtE[idx];
    }
    __syncthreads();
    int w = t >> 6, lane = t & 63, row16 = lane & 15, kg = lane >> 4;
    f32x4 acc[4];
#pragma unroll
    for (int n = 0; n < 4; ++n) acc[n] = (f32x4){0.f, 0.f, 0.f, 0.f};
#pragma unroll
    for (int ks = 0; ks < 3; ++ks) {
        int pbase = ks * 16 + kg * 4;
        bf16x8 a = *(const bf16x8*)&zsu[w * 16 + row16][pbase];
#pragma unroll
        for (int n = 0; n < 4; ++n) {
            bf16x8 b = *(const bf16x8*)&btu[n * 16 + row16][pbase];
            acc[n] = __builtin_amdgcn_mfma_f32_16x16x32_bf16(a, b, acc[n], 0, 0, 0);
        }
    }
#pragma unroll
    for (int i = 0; i < 4; ++i) {
        int node = node0 + w * 16 + kg * 4 + i;
        if (node < N_NODES) {
            bool has = ncnt[node] > 0;
#pragma unroll
            for (int n = 0; n < 4; ++n) {
                int d = n * 16 + row16;
                float nv = acc[n][i] + be[d];
                h[node * 64 + d] = nv;
                float other = __shfl_xor(nv, 1);
                if ((d & 1) == 0) {
                    unsigned pr = f2_to_bf2(nv, other);
                    hb[node * 32 + (d >> 1)] = pr;
                    zb[(size_t)node * KPAIRS + (d >> 1)] = has ? pr : 0u;
                }
            }
        }
    }
}

// ---------- hattr -> bf16 padded mirror ----------
__global__ void attrconv_k(const float* __restrict__ hattr, unsigned* __restrict__ hab) {
    int idx = blockIdx.x * 256 + threadIdx.x;
    if (idx >= N_HEDGES * ATTR_PAIRS) return;
    int e = idx / ATTR_PAIRS, p = idx - e * ATTR_PAIRS;
    int d0 = 2 * p, d1 = 2 * p + 1;
    float v0 = hattr[e * ATTR_DIM + d0];
    float v1 = (d1 < ATTR_DIM) ? hattr[e * ATTR_DIM + d1] : 0.f;
    hab[idx] = f2_to_bf2(v0, v1);
}

// ---------- layer weights -> Bt bf16 [l][c=128][k pairs=96] ----------
__global__ void btpack_k(const float* __restrict__ Wf, const float* __restrict__ Wc,
                         unsigned* __restrict__ Btb) {
    int idx = blockIdx.x * 256 + threadIdx.x;
    if (idx >= N_LAYERS * 128 * KPAIRS) return;
    int l = idx / (128 * KPAIRS);
    int rem = idx - l * 128 * KPAIRS;
    int c = rem / KPAIRS, p = rem - c * KPAIRS;
    int k0 = 2 * p, k1 = 2 * p + 1;
    const float* W = (c < 64) ? (Wf + (size_t)l * MSG_DIM * 64) : (Wc + (size_t)l * MSG_DIM * 64);
    int cc = c & 63;
    float v0 = (k0 < MSG_DIM) ? W[k0 * 64 + cc] : 0.f;
    float v1 = (k1 < MSG_DIM) ? W[k1 * 64 + cc] : 0.f;
    Btb[idx] = f2_to_bf2(v0, v1);
}

// ---------- fused sort S1: both histograms in one pass over inc arrays ----------
__global__ void sorthist2_k(const int* __restrict__ keyE, const int* __restrict__ keyN,
                            int* __restrict__ histE, int* __restrict__ histN) {
    __shared__ int cntE[NB_E], cntN[NB_N];
    int blk = blockIdx.x;
    for (int i = threadIdx.x; i < NB_E; i += 256) cntE[i] = 0;
    for (int i = threadIdx.x; i < NB_N; i += 256) cntN[i] = 0;
    __syncthreads();
    int base = blk * IPB;
    int end = min(base + IPB, N_INCID);
    for (int i = base + threadIdx.x; i < end; i += 256) {
        atomicAdd(&cntE[keyE[i] >> ESHIFT], 1);
        atomicAdd(&cntN[keyN[i] >> NSHIFT], 1);
    }
    __syncthreads();
    for (int i = threadIdx.x; i < NB_E; i += 256) histE[blk * NB_E + i] = cntE[i];
    for (int i = threadIdx.x; i < NB_N; i += 256) histN[blk * NB_N + i] = cntN[i];
}

// ---------- scan with bucket-major remap ----------
__global__ void scanR1_k(const int* __restrict__ in, int* __restrict__ out,
                         int* __restrict__ bsum, int n, int NB) {
    __shared__ int tmp[256];
    int gid = blockIdx.x * 256 + threadIdx.x;
    int v = 0;
    if (gid < n) {
        int bucket = gid / NBLK, blk = gid - bucket * NBLK;
        v = in[blk * NB + bucket];
    }
    tmp[threadIdx.x] = v;
    __syncthreads();
    for (int o = 1; o < 256; o <<= 1) {
        int t = (threadIdx.x >= o) ? tmp[threadIdx.x - o] : 0;
        __syncthreads();
        tmp[threadIdx.x] += t;
        __syncthreads();
    }
    if (gid < n) out[gid] = tmp[threadIdx.x] - v;
    if (threadIdx.x == 255) bsum[blockIdx.x] = tmp[255];
}

__global__ void scan2_k(int* __restrict__ bsum, int nb) {
    __shared__ int tmp[256];
    __shared__ int carry;
    if (threadIdx.x == 0) carry = 0;
    __syncthreads();
    for (int base = 0; base < nb; base += 256) {
        int gid = base + threadIdx.x;
        int v = (gid < nb) ? bsum[gid] : 0;
        tmp[threadIdx.x] = v;
        __syncthreads();
        for (int o = 1; o < 256; o <<= 1) {
            int t = (threadIdx.x >= o) ? tmp[threadIdx.x - o] : 0;
            __syncthreads();
            tmp[threadIdx.x] += t;
            __syncthreads();
        }
        if (gid < nb) bsum[gid] = tmp[threadIdx.x] - v + carry;
        __syncthreads();
        if (threadIdx.x == 0) carry += tmp[255];
        __syncthreads();
    }
}

__global__ void scan3_k(int* __restrict__ out, const int* __restrict__ bsum, int n) {
    int gid = blockIdx.x * 256 + threadIdx.x;
    if (gid < n) out[gid] += bsum[blockIdx.x];
}

// ---------- fused sort S3: both scatters in one pass ----------
__global__ void sortscat2_k(const int* __restrict__ keyE, const int* __restrict__ keyN,
                            const int* __restrict__ soffE, const int* __restrict__ soffN,
                            unsigned* __restrict__ stageE, unsigned* __restrict__ stageN) {
    __shared__ int curE[NB_E], basE[NB_E], curN[NB_N], basN[NB_N];
    int blk = blockIdx.x;
    for (int i = threadIdx.x; i < NB_E; i += 256) { curE[i] = 0; basE[i] = soffE[i * NBLK + blk]; }
    for (int i = threadIdx.x; i < NB_N; i += 256) { curN[i] = 0; basN[i] = soffN[i * NBLK + blk]; }
    __syncthreads();
    int base = blk * IPB;
    int end = min(base + IPB, N_INCID);
    for (int i = base + threadIdx.x; i < end; i += 256) {
        int kE = keyE[i], kN = keyN[i];
        int bE = kE >> ESHIFT;
        int dE = basE[bE] + atomicAdd(&curE[bE], 1);
        stageE[dE] = (((unsigned)kE & ((1u << ESHIFT) - 1u)) << VALBITS) | (unsigned)kN;
        int bN = kN >> NSHIFT;
        int dN = basN[bN] + atomicAdd(&curN[bN], 1);
        stageN[dN] = (((unsigned)kN & ((1u << NSHIFT) - 1u)) << VALBITS) | (unsigned)kE;
    }
}

// ---------- sort S4: fine counting-sort within bucket ----------
__global__ void sortfine_k(const unsigned* __restrict__ stage, const int* __restrict__ soff,
                           int* __restrict__ csr, int* __restrict__ koff,
                           float* __restrict__ krcp, int* __restrict__ kcnt,
                           int kshift, int NB, int NKEYS) {
    __shared__ int cnt[512], off[512], cur[512];
    __shared__ int ts[256];
    int b = blockIdx.x;
    int tid = threadIdx.x;
    int KPB = 1 << kshift;
    int kbase = b << kshift;
    int base = soff[b * NBLK];
    int end = (b == NB - 1) ? N_INCID : soff[(b + 1) * NBLK];
    for (int i = tid; i < KPB; i += 256) cnt[i] = 0;
    __syncthreads();
    for (int i = base + tid; i < end; i += 256)
        atomicAdd(&cnt[stage[i] >> VALBITS], 1);
    __syncthreads();
    int half = KPB >> 1;
    int c0 = 0, c1 = 0;
    if (tid < half) { c0 = cnt[2 * tid]; c1 = cnt[2 * tid + 1]; ts[tid] = c0 + c1; }
    __syncthreads();
    for (int o = 1; o < 256; o <<= 1) {
        int v = (tid >= o && tid < half) ? ts[tid - o] : 0;
        __syncthreads();
        if (tid < half) ts[tid] += v;
        __syncthreads();
    }
    if (tid < half) {
        int ex = ts[tid] - (c0 + c1);
        off[2 * tid] = ex;
        off[2 * tid + 1] = ex + c0;
    }
    __syncthreads();
    for (int k = tid; k < KPB; k += 256) {
        int gk = kbase + k;
        if (gk < NKEYS) {
            koff[gk] = base + off[k];
            krcp[gk] = 1.0f / (float)max(cnt[k], 1);
            kcnt[gk] = cnt[k];
        }
        cur[k] = 0;
    }
    __syncthreads();
    for (int i = base + tid; i < end; i += 256) {
        unsigned it = stage[i];
        int lk = (int)(it >> VALBITS);
        int pos = base + off[lk] + atomicAdd(&cur[lk], 1);
        csr[pos] = (int)(it & ((1u << VALBITS) - 1u));
    }
}

__global__ void sentinel_k(int* __restrict__ eoff, int* __restrict__ noff) {
    if (threadIdx.x == 0) eoff[N_HEDGES] = N_INCID;
    if (threadIdx.x == 1) noff[N_NODES] = N_INCID;
}

// ---------- per-hedge mean: 8-lane sub-group per hedge, windows of 8 members,
// all 8 row-loads in flight, no cross-lane reduction ----------
__global__ void hmean_k(const int* __restrict__ eoff, const int* __restrict__ csr_en,
                        const uint4* __restrict__ hbv4, const float* __restrict__ ercp,
                        uint4* __restrict__ hmv4) {
    int idx = blockIdx.x * 256 + threadIdx.x;
    int e = idx >> 3, il = idx & 7;
    if (e >= N_HEDGES) return;
    int s = eoff[e], t = eoff[e + 1];
    float a0 = 0, a1 = 0, a2 = 0, a3 = 0, a4 = 0, a5 = 0, a6 = 0, a7 = 0;
    for (int base = s; base < t; base += 8) {
        int cnt = t - base;  // window handles min(8, cnt)
        int myidx = (base + il < t) ? csr_en[base + il] : 0;
        uint4 v[8];
#pragma unroll
        for (int m = 0; m < 8; ++m) {
            int nq = __shfl(myidx, m, 8);
            v[m] = (m < cnt) ? hbv4[nq * 8 + il] : make_uint4(0u, 0u, 0u, 0u);
        }
#pragma unroll
        for (int m = 0; m < 8; ++m) {
            a0 += u2f(v[m].x << 16); a1 += u2f(v[m].x);
            a2 += u2f(v[m].y << 16); a3 += u2f(v[m].y);
            a4 += u2f(v[m].z << 16); a5 += u2f(v[m].z);
            a6 += u2f(v[m].w << 16); a7 += u2f(v[m].w);
        }
    }
    float rc = ercp[e];
    hmv4[e * 8 + il] = make_uint4(f2_to_bf2(a0 * rc, a1 * rc), f2_to_bf2(a2 * rc, a3 * rc),
                                  f2_to_bf2(a4 * rc, a5 * rc), f2_to_bf2(a6 * rc, a7 * rc));
}

// ---------- per-node mean of hmean -> zb uint4 slots 8..15 (same 8-lane structure) ----------
__global__ void nodeh_k(const int* __restrict__ noff, const int* __restrict__ csr_ne,
                        const uint4* __restrict__ hmv4, const float* __restrict__ nrcp,
                        uint4* __restrict__ zbv4) {
    int idx = blockIdx.x * 256 + threadIdx.x;
    int n = idx >> 3, il = idx & 7;
    if (n >= N_NODES) return;
    int s = noff[n], t = noff[n + 1];
    float a0 = 0, a1 = 0, a2 = 0, a3 = 0, a4 = 0, a5 = 0, a6 = 0, a7 = 0;
    for (int base = s; base < t; base += 8) {
        int cnt = t - base;
        int myidx = (base + il < t) ? csr_ne[base + il] : 0;
        uint4 v[8];
#pragma unroll
        for (int m = 0; m < 8; ++m) {
            int eq = __shfl(myidx, m, 8);
            v[m] = (m < cnt) ? hmv4[eq * 8 + il] : make_uint4(0u, 0u, 0u, 0u);
        }
#pragma unroll
        for (int m = 0; m < 8; ++m) {
            a0 += u2f(v[m].x << 16); a1 += u2f(v[m].x);
            a2 += u2f(v[m].y << 16); a3 += u2f(v[m].y);
            a4 += u2f(v[m].z << 16); a5 += u2f(v[m].z);
            a6 += u2f(v[m].w << 16); a7 += u2f(v[m].w);
        }
    }
    float rc = nrcp[n];
    zbv4[(size_t)n * 24 + 8 + il] =
        make_uint4(f2_to_bf2(a0 * rc, a1 * rc), f2_to_bf2(a2 * rc, a3 * rc),
                   f2_to_bf2(a4 * rc, a5 * rc), f2_to_bf2(a6 * rc, a7 * rc));
}

// ---------- per-node mean of hedge_attr -> zb pairs 64..95 (one-time; uint2 guarded) ----------
__global__ void nodea_k(const int* __restrict__ noff, const int* __restrict__ csr_ne,
                        const uint2* __restrict__ habv, const float* __restrict__ nrcp,
                        uint2* __restrict__ zbv) {
    int idx = blockIdx.x * 256 + threadIdx.x;
    int n = idx >> 5, l = idx & 31;
    if (n >= N_NODES) return;
    int sub = l >> 4, q = l & 15;
    bool act = (q < ATTR_PAIRS / 2);
    int s = noff[n], t = noff[n + 1];
    float a0 = 0.f, a1 = 0.f, a2 = 0.f, a3 = 0.f;
    for (int base = s; base < t; base += 32) {
        int cnt = min(32, t - base);
        int myidx = (base + l < t) ? csr_ne[base + l] : 0;
        for (int j = 0; j < cnt; j += 16) {
            uint2 v[8];
#pragma unroll
            for (int w = 0; w < 8; ++w) {
                int mem = j + 2 * w + sub;
                int eq = __shfl(myidx, mem, 32);
                v[w] = (act && mem < cnt) ? habv[eq * (ATTR_PAIRS / 2) + q] : make_uint2(0u, 0u);
            }
#pragma unroll
            for (int w = 0; w < 8; ++w) {
                a0 += u2f(v[w].x << 16); a1 += u2f(v[w].x);
                a2 += u2f(v[w].y << 16); a3 += u2f(v[w].y);
            }
        }
    }
    a0 += __shfl_xor(a0, 16);
    a1 += __shfl_xor(a1, 16);
    a2 += __shfl_xor(a2, 16);
    a3 += __shfl_xor(a3, 16);
    if (sub == 0) {
        float rc = nrcp[n];
        uint2 pr = act ? make_uint2(f2_to_bf2(a0 * rc, a1 * rc), f2_to_bf2(a2 * rc, a3 * rc))
                       : make_uint2(0u, 0u);
        zbv[(size_t)n * (KPAIRS / 2) + 32 + q] = pr;
    }
}

// ---------- layer GEMM via MFMA; B in registers, A in LDS ----------
__global__ void __launch_bounds__(256)
layer_mfma_k(const unsigned* __restrict__ Btl, const float* __restrict__ bfv,
             const float* __restrict__ bcv, const int* __restrict__ ncnt,
             unsigned* __restrict__ zb, float* __restrict__ h,
             unsigned* __restrict__ hb) {
    __shared__ unsigned zsu[64][ZLDS];
    int node0 = blockIdx.x * 64;
    int t = threadIdx.x;
    int w = t >> 6, lane = t & 63;
    int row16 = lane & 15, kg = lane >> 4;

    uint4 bregF[6], bregC[6];
    {
        const uint4* bv = (const uint4*)Btl;
        int colF = w * 16 + row16;
        int colC = colF + 64;
#pragma unroll
        for (int ks = 0; ks < 6; ++ks) {
            bregF[ks] = bv[colF * 24 + ks * 4 + kg];
            bregC[ks] = bv[colC * 24 + ks * 4 + kg];
        }
    }
    {
        const uint4* zv = (const uint4*)zb;
        for (int idx = t; idx < 64 * 24; idx += 256) {
            int r = idx / 24, p4 = idx - r * 24;
            int node = node0 + r;
            uint4 v = make_uint4(0u, 0u, 0u, 0u);
            if (node < N_NODES) v = zv[(size_t)node * 24 + p4];
            *(uint4*)&zsu[r][p4 * 4] = v;
        }
    }
    __syncthreads();

    f32x4 accF[4], accC[4];
#pragma unroll
    for (int n = 0; n < 4; ++n) {
        accF[n] = (f32x4){0.f, 0.f, 0.f, 0.f};
        accC[n] = (f32x4){0.f, 0.f, 0.f, 0.f};
    }

#pragma unroll
    for (int ks = 0; ks < 6; ++ks) {
        int pbase = ks * 16 + kg * 4;
        bf16x8 bF = *(const bf16x8*)&bregF[ks];
        bf16x8 bC = *(const bf16x8*)&bregC[ks];
#pragma unroll
        for (int rb = 0; rb < 4; ++rb) {
            bf16x8 a = *(const bf16x8*)&zsu[rb * 16 + row16][pbase];
            accF[rb] = __builtin_amdgcn_mfma_f32_16x16x32_bf16(a, bF, accF[rb], 0, 0, 0);
            accC[rb] = __builtin_amdgcn_mfma_f32_16x16x32_bf16(a, bC, accC[rb], 0, 0, 0);
        }
    }

    int d = w * 16 + row16;
    float bfd = bfv[d], bcd = bcv[d];
#pragma unroll
    for (int rb = 0; rb < 4; ++rb) {
#pragma unroll
        for (int i = 0; i < 4; ++i) {
            int node = node0 + rb * 16 + kg * 4 + i;
            if (node < N_NODES) {
                bool has = ncnt[node] > 0;
                float f = accF[rb][i] + bfd;
                float c = accC[rb][i] + bcd;
                float hv = h[node * 64 + d];
                float nv = softplusf(sigmoidf(f) * softplusf(c) + hv);
                h[node * 64 + d] = nv;
                float other = __shfl_xor(nv, 1);
                if ((d & 1) == 0) {
                    unsigned pr = f2_to_bf2(nv, other);
                    hb[node * 32 + (d >> 1)] = pr;
                    zb[(size_t)node * KPAIRS + (d >> 1)] = has ? pr : 0u;
                }
            }
        }
    }
}

// ---------- per-graph boundaries ----------
__global__ void gstart_k(const int* __restrict__ batch, int* __restrict__ gstart) {
    int g = blockIdx.x * 256 + threadIdx.x;
    if (g > N_GRAPHS) return;
    int lo = 0, hi = N_NODES;
    while (lo < hi) {
        int mid = (lo + hi) >> 1;
        if (batch[mid] < g) lo = mid + 1; else hi = mid;
    }
    gstart[g] = lo;
}

// ---------- fused pool + proj + out ----------
__global__ void poolhead_k(const float* __restrict__ h, const int* __restrict__ gstart,
                           const float* __restrict__ Wp, const float* __restrict__ bp,
                           const float* __restrict__ Wo, const float* __restrict__ bo,
                           float* __restrict__ out) {
    __shared__ float partial[4][64];
    __shared__ float pm[64];
    __shared__ float pr[128];
    int g = blockIdx.x, t = threadIdx.x;
    int s = gstart[g], e = gstart[g + 1];
    int w = t >> 6, lane = t & 63;
    float acc = 0.f;
    for (int n = s + w; n < e; n += 4) acc += h[n * 64 + lane];
    partial[w][lane] = acc;
    __syncthreads();
    if (t < 64) {
        float c = fmaxf((float)(e - s), 1.0f);
        pm[t] = (partial[0][t] + partial[1][t] + partial[2][t] + partial[3][t]) / c;
    }
    __syncthreads();
    if (t < 128) {
        float a = bp[t];
#pragma unroll 4
        for (int k = 0; k < 64; ++k) a += pm[k] * Wp[k * HOUT_DIM + t];
        pr[t] = softplusf(a) * Wo[t];
    }
    __syncthreads();
    if (t < 64) {
        float v = pr[t] + pr[t + 64];
        for (int o = 32; o > 0; o >>= 1) v += __shfl_down(v, o);
        if (t == 0) out[g] = v + bo[0];
    }
}

extern "C" void kernel_launch(void* const* d_in, const int* in_sizes, int n_in,
                              void* d_out, int out_size, void* d_ws, size_t ws_size,
                              hipStream_t stream) {
    const float* x       = (const float*)d_in[0];
    const int*   inc_n   = (const int*)d_in[1];
    const int*   inc_e   = (const int*)d_in[2];
    const float* hattr   = (const float*)d_in[3];
    const int*   batch   = (const int*)d_in[4];
    const float* W_embed = (const float*)d_in[5];
    const float* b_embed = (const float*)d_in[6];
    const float* Wf      = (const float*)d_in[7];
    const float* bf      = (const float*)d_in[8];
    const float* Wc      = (const float*)d_in[9];
    const float* bc      = (const float*)d_in[10];
    const float* W_proj  = (const float*)d_in[11];
    const float* b_proj  = (const float*)d_in[12];
    const float* W_out   = (const float*)d_in[13];
    const float* b_out   = (const float*)d_in[14];
    float* out = (float*)d_out;

    char* ws = (char*)d_ws;
    size_t off = 0;
    auto alloc = [&](size_t bytes) {
        void* p = ws + off;
        off = (off + bytes + 255) & ~(size_t)255;
        return p;
    };
    float*    h      = (float*)alloc((size_t)N_NODES * 64 * 4);
    unsigned* hb     = (unsigned*)alloc((size_t)N_NODES * 32 * 4);
    unsigned* hmean  = (unsigned*)alloc((size_t)N_HEDGES * 32 * 4);  // aliases both sort stagings
    unsigned* zb     = (unsigned*)alloc((size_t)N_NODES * KPAIRS * 4);
    unsigned* hab    = (unsigned*)alloc((size_t)N_HEDGES * ATTR_PAIRS * 4);
    unsigned* Btb    = (unsigned*)alloc((size_t)N_LAYERS * 128 * KPAIRS * 4);
    unsigned* BtE    = (unsigned*)alloc((size_t)64 * EPAIRS * 4);
    int*      ncnt   = (int*)alloc((size_t)N_NODES * 4);
    int*      ecnt   = (int*)alloc((size_t)N_HEDGES * 4);
    float*    nrcp   = (float*)alloc((size_t)N_NODES * 4);
    float*    ercp   = (float*)alloc((size_t)N_HEDGES * 4);
    int*      eoff   = (int*)alloc((size_t)(N_HEDGES + 1) * 4);
    int*      noff   = (int*)alloc((size_t)(N_NODES + 1) * 4);
    int*      csr_en = (int*)alloc((size_t)N_INCID * 4);
    int*      csr_ne = (int*)alloc((size_t)N_INCID * 4);
    int*      histE  = (int*)alloc((size_t)NB_E * NBLK * 4);
    int*      histN  = (int*)alloc((size_t)NB_N * NBLK * 4);
    int*      soffE  = (int*)alloc((size_t)NB_E * NBLK * 4);
    int*      soffN  = (int*)alloc((size_t)NB_N * NBLK * 4);
    int*      bsum   = (int*)alloc((size_t)2048 * 4);
    int*      gstart = (int*)alloc((size_t)(N_GRAPHS + 1) * 4);
    unsigned* stageE = (unsigned*)hmean;                 // 8 MB
    unsigned* stageN = (unsigned*)hmean + N_INCID;       // next 8 MB (hmean is 38.4 MB)

    // ---- fused histograms ----
    sorthist2_k<<<NBLK, 256, 0, stream>>>(inc_e, inc_n, histE, histN);
    // ---- scans ----
    {
        int nlogE = NB_E * NBLK, nsbE = (nlogE + 255) / 256;
        scanR1_k<<<nsbE, 256, 0, stream>>>(histE, soffE, bsum, nlogE, NB_E);
        scan2_k<<<1, 256, 0, stream>>>(bsum, nsbE);
        scan3_k<<<nsbE, 256, 0, stream>>>(soffE, bsum, nlogE);
        int nlogN = NB_N * NBLK, nsbN = (nlogN + 255) / 256;
        scanR1_k<<<nsbN, 256, 0, stream>>>(histN, soffN, bsum, nlogN, NB_N);
        scan2_k<<<1, 256, 0, stream>>>(bsum, nsbN);
        scan3_k<<<nsbN, 256, 0, stream>>>(soffN, bsum, nlogN);
    }
    // ---- fused scatter + fine sorts ----
    sortscat2_k<<<NBLK, 256, 0, stream>>>(inc_e, inc_n, soffE, soffN, stageE, stageN);
    sortfine_k<<<NB_E, 256, 0, stream>>>(stageE, soffE, csr_en, eoff, ercp, ecnt,
                                         ESHIFT, NB_E, N_HEDGES);
    sortfine_k<<<NB_N, 256, 0, stream>>>(stageN, soffN, csr_ne, noff, nrcp, ncnt,
                                         NSHIFT, NB_N, N_NODES);
    sentinel_k<<<1, 64, 0, stream>>>(eoff, noff);

    embpack_k<<<(64 * EPAIRS + 255) / 256, 256, 0, stream>>>(W_embed, BtE);
    embed_mfma_k<<<(N_NODES + 63) / 64, 256, 0, stream>>>(x, BtE, b_embed, ncnt, h, hb, zb);
    attrconv_k<<<(N_HEDGES * ATTR_PAIRS + 255) / 256, 256, 0, stream>>>(hattr, hab);
    btpack_k<<<(N_LAYERS * 128 * KPAIRS + 255) / 256, 256, 0, stream>>>(Wf, Wc, Btb);
    nodea_k<<<(N_NODES * 32) / 256, 256, 0, stream>>>(noff, csr_ne, (const uint2*)hab, nrcp,
                                                      (uint2*)zb);

    for (int l = 0; l < N_LAYERS; ++l) {
        hmean_k<<<(N_HEDGES * 8) / 256, 256, 0, stream>>>(eoff, csr_en, (const uint4*)hb, ercp,
                                                          (uint4*)hmean);
        nodeh_k<<<(N_NODES * 8) / 256, 256, 0, stream>>>(noff, csr_ne, (const uint4*)hmean, nrcp,
                                                         (uint4*)zb);
        layer_mfma_k<<<(N_NODES + 63) / 64, 256, 0, stream>>>(Btb + (size_t)l * 128 * KPAIRS,
                                                              bf + l * 64, bc + l * 64,
                                                              ncnt, zb, h, hb);
    }
    gstart_k<<<(N_GRAPHS + 1 + 255) / 256, 256, 0, stream>>>(batch, gstart);
    poolhead_k<<<N_GRAPHS, 256, 0, stream>>>(h, gstart, W_proj, b_proj, W_out, b_out, out);
}